// Round 13
// baseline (180.431 us; speedup 1.0000x reference)
//
#include <hip/hip_runtime.h>
#include <hip/hip_bf16.h>

// Problem constants
#define BB 2
#define LL 2048
#define DD 512
#define HH 8
#define HDM 64
#define SCALE 0.022097086912079608f    // 1/sqrt(2048)
#define QSCALE 0.03187935766f          // SCALE * log2(e)  (exp2-domain softmax)

typedef __hip_bfloat16 bf16;
typedef unsigned short u16;
typedef __attribute__((ext_vector_type(8))) short short8v;   // 8 bf16 (4 VGPRs)
typedef __attribute__((ext_vector_type(4))) float float4v;   // 4 fp32 acc

// Input element counts
#define XN  2097152    // 2*2048*512
#define WN  2359296    // 1536*512*3
#define BN  1536
#define FWN 262144     // 512*512
#define FBN 512

__device__ __forceinline__ float b2f(u16 u) {
    return __uint_as_float(((unsigned int)u) << 16);
}
__device__ __forceinline__ u16 f2u(float f) {
    bf16 h = __float2bfloat16(f);
    u16 r;
    __builtin_memcpy(&r, &h, 2);
    return r;
}
__device__ __forceinline__ uint4 pack8(const float* f) {
    uint4 p;
    p.x = (unsigned)f2u(f[0]) | ((unsigned)f2u(f[1]) << 16);
    p.y = (unsigned)f2u(f[2]) | ((unsigned)f2u(f[3]) << 16);
    p.z = (unsigned)f2u(f[4]) | ((unsigned)f2u(f[5]) << 16);
    p.w = (unsigned)f2u(f[6]) | ((unsigned)f2u(f[7]) << 16);
    return p;
}

// async 16-B global -> LDS copy (lds dest = wave-uniform base + lane*16)
__device__ __forceinline__ void gld_lds16(const u16* g, u16* l) {
    __builtin_amdgcn_global_load_lds(
        (const __attribute__((address_space(1))) unsigned int*)g,
        (__attribute__((address_space(3))) unsigned int*)l, 16, 0, 0);
}

// -------------------------------------------------------------------------
// Kernel 0: dtype detect (f32 vs bf16 inputs). See R1 notes.
// -------------------------------------------------------------------------
__global__ void detect_kernel(const u16* __restrict__ x, int* __restrict__ flag) {
    int bad = 0;
    for (int i = threadIdx.x; i < 256; i += 64) {
        float v = b2f(x[i]);
        if (!(fabsf(v) < 100.f)) bad = 1;   // catches NaN too
    }
    unsigned long long m = __ballot(bad);
    if (threadIdx.x == 0) *flag = (m != 0ull) ? 1 : 0;
}

__device__ __forceinline__ void conv8(const void* src, u16* dst, size_t i, int flag) {
    if (flag) {
        const float* s = (const float*)src;
        float f[8];
        float4 a = *(const float4*)(s + i);
        float4 b = *(const float4*)(s + i + 4);
        f[0] = a.x; f[1] = a.y; f[2] = a.z; f[3] = a.w;
        f[4] = b.x; f[5] = b.y; f[6] = b.z; f[7] = b.w;
        *(uint4*)(dst + i) = pack8(f);
    } else {
        *(uint4*)(dst + i) = *(const uint4*)((const u16*)src + i);
    }
}

// -------------------------------------------------------------------------
// Kernel 0a: fused small converts: cnn_b (1536) + fc_w (262144) + fc_b (512)
// -------------------------------------------------------------------------
__global__ __launch_bounds__(256) void convert_small_kernel(
    const void* __restrict__ bsrc, const void* __restrict__ fwsrc,
    const void* __restrict__ fbsrc,
    u16* __restrict__ bc, u16* __restrict__ fwc, u16* __restrict__ fbc,
    const int* __restrict__ flagp)
{
    const int flag = *flagp;
    int o = blockIdx.x * 256 + threadIdx.x;          // octet id
    if (o < BN / 8) {
        conv8(bsrc, bc, (size_t)o * 8, flag);
    } else if (o < BN / 8 + FWN / 8) {
        conv8(fwsrc, fwc, (size_t)(o - BN / 8) * 8, flag);
    } else if (o < BN / 8 + FWN / 8 + FBN / 8) {
        conv8(fbsrc, fbc, (size_t)(o - BN / 8 - FWN / 8) * 8, flag);
    }
}

// -------------------------------------------------------------------------
// Kernel 0b': x -> zero-guard-padded xp[B][2050][512]; threads 0..255 also
// zero the guard rows (merged zeropad).
// -------------------------------------------------------------------------
__global__ __launch_bounds__(256) void convert_xpad_kernel(
    const void* __restrict__ src, u16* __restrict__ xp,
    const int* __restrict__ flagp)
{
    const int flag = *flagp;
    int idx = blockIdx.x * 256 + threadIdx.x;     // octet id, < 2*2048*64
    if (idx < 256) {
        int b2  = idx >> 7;
        int r2  = (idx >> 6) & 1;
        int c82 = (idx & 63) * 8;
        size_t off = ((size_t)(b2 * 2050 + (r2 ? 2049 : 0))) * 512 + c82;
        uint4 z = {0u, 0u, 0u, 0u};
        *(uint4*)(xp + off) = z;
    }
    if (idx >= BB * LL * 64) return;
    int b   = idx / (LL * 64);
    int rem = idx - b * (LL * 64);
    int l   = rem >> 6;
    int c8  = (rem & 63) * 8;
    size_t si = ((size_t)(b * LL + l)) * 512 + c8;
    size_t di = ((size_t)(b * 2050 + l + 1)) * 512 + c8;
    if (flag) {
        const float* s = (const float*)src;
        float f[8];
        float4 a = *(const float4*)(s + si);
        float4 bq = *(const float4*)(s + si + 4);
        f[0] = a.x; f[1] = a.y; f[2] = a.z; f[3] = a.w;
        f[4] = bq.x; f[5] = bq.y; f[6] = bq.z; f[7] = bq.w;
        *(uint4*)(xp + di) = pack8(f);
    } else {
        *(uint4*)(xp + di) = *(const uint4*)((const u16*)src + si);
    }
}

// -------------------------------------------------------------------------
// Kernel 0c: cnn_w canonicalize + transpose [o][i][k] -> [o][k*512+i].
// -------------------------------------------------------------------------
__global__ __launch_bounds__(256) void convw_kernel(
    const void* __restrict__ src, u16* __restrict__ wt,
    const int* __restrict__ flagp)
{
    const int flag = *flagp;
    int idx = blockIdx.x * 256 + threadIdx.x;   // < 1536*3*64
    int i8  = idx & 63;
    int rem = idx >> 6;
    int k   = rem % 3;
    int o   = rem / 3;
    float f[8];
    if (flag) {
        const float* s = (const float*)src;
#pragma unroll
        for (int j = 0; j < 8; ++j) f[j] = s[(size_t)o * 1536 + (i8 * 8 + j) * 3 + k];
    } else {
        const u16* s = (const u16*)src;
#pragma unroll
        for (int j = 0; j < 8; ++j) f[j] = b2f(s[(size_t)o * 1536 + (i8 * 8 + j) * 3 + k]);
    }
    *(uint4*)(wt + (size_t)o * 1536 + k * 512 + i8 * 8) = pack8(f);
}

// -------------------------------------------------------------------------
// Kernel 1: conv GEMM, m97-style K-loop + XOR bank swizzle. (unchanged R12)
// -------------------------------------------------------------------------
__global__ __launch_bounds__(256) void conv_mfma_kernel(
    const u16* __restrict__ xp,     // [B][2050][512] padded bf16
    const u16* __restrict__ wt,     // [1536][1536] = [o][k*512+i]
    const u16* __restrict__ bias,   // [1536]
    u16* __restrict__ qkbuf,        // [B*H][2][L][64]
    u16* __restrict__ vbuf)         // [B*H][64][L]
{
    __shared__ u16 smem[32768];     // 65536 B
    u16* Asb = smem;                // [2][128][64] unpadded, swizzled
    u16* Bsb = smem + 2 * 128 * 64; // [2][128][64] unpadded, swizzled
#define OTS 140
    u16* OT  = smem;                // [128][140] aliased after final sync

    const int blk = blockIdx.x;          // rt*12 + ct
    const int rt = blk / 12;
    const int ct = blk - rt * 12;
    const int b  = rt >> 4;
    const int l0 = (rt & 15) * 128;
    const int tid  = threadIdx.x;
    const int wave = tid >> 6;
    const int lane = tid & 63;
    const int quad = lane >> 4;
    const int l16  = lane & 15;
    const int e7   = l16 & 7;
    const int wx = wave & 1;             // n half
    const int wy = wave >> 1;            // m half

    float4v acc[4][4];
#pragma unroll
    for (int mt = 0; mt < 4; ++mt)
#pragma unroll
        for (int nt = 0; nt < 4; ++nt) acc[mt][nt] = (float4v){0.f, 0.f, 0.f, 0.f};

    const int rowW = wave * 32;
    const int lrow = lane >> 3;          // 0..7
    const int g8   = (((lane & 7) ^ lrow)) * 8;
    auto stage = [&](int kc, int buf) {
        const int slab = kc >> 3;                // conv tap k (0..2)
        const int i0   = (kc & 7) * 64;          // input-channel slice
        const u16* ga = xp + ((size_t)(b * 2050 + l0 + rowW + slab + lrow)) * 512 + i0 + g8;
        const u16* gb = wt + ((size_t)(ct * 128 + rowW + lrow)) * 1536 + kc * 64 + g8;
        u16* la = Asb + (size_t)(buf * 128 + rowW) * 64;
        u16* lb = Bsb + (size_t)(buf * 128 + rowW) * 64;
#pragma unroll
        for (int j = 0; j < 4; ++j) {
            gld_lds16(ga + (size_t)(j * 8) * 512,  la + (j * 8) * 64);
            gld_lds16(gb + (size_t)(j * 8) * 1536, lb + (j * 8) * 64);
        }
    };

    stage(0, 0);

    for (int kc = 0; kc < 24; ++kc) {
        const int cur = kc & 1;
        __syncthreads();   // drains vmcnt -> chunk kc staged; prev reads done

        if (kc < 23) stage(kc + 1, 1 - cur);

#pragma unroll
        for (int half = 0; half < 2; ++half) {
            const int p = ((half * 4 + quad) ^ e7) * 8;   // swizzled chunk
            short8v aF[4], bF[4];
#pragma unroll
            for (int mt = 0; mt < 4; ++mt)
                aF[mt] = *(const short8v*)&Asb[(size_t)(cur * 128 + wy * 64 + mt * 16 + l16) * 64 + p];
#pragma unroll
            for (int nt = 0; nt < 4; ++nt)
                bF[nt] = *(const short8v*)&Bsb[(size_t)(cur * 128 + wx * 64 + nt * 16 + l16) * 64 + p];
#pragma unroll
            for (int mt = 0; mt < 4; ++mt)
#pragma unroll
                for (int nt = 0; nt < 4; ++nt)
                    acc[mt][nt] = __builtin_amdgcn_mfma_f32_16x16x32_bf16(
                        aF[mt], bF[nt], acc[mt][nt], 0, 0, 0);
        }
    }

    // ---- epilogue stage 1: bias+swish(+QSCALE) in regs -> OT [128 l][128 o]
    __syncthreads();   // all LDS tile reads done; safe to alias as OT
    {
        const int tloc = (ct * 2 + wx) % 3;   // t for this wave's col group
#pragma unroll
        for (int nt = 0; nt < 4; ++nt) {
            int oc = wx * 64 + nt * 16 + l16;           // tile-local col
            float bb = b2f(bias[ct * 128 + oc]);
#pragma unroll
            for (int mt = 0; mt < 4; ++mt)
#pragma unroll
                for (int r = 0; r < 4; ++r) {
                    int lr = wy * 64 + mt * 16 + quad * 4 + r;   // tile-local row
                    float y = acc[mt][nt][r] + bb;
                    y = y / (1.f + __expf(-y));                  // swish
                    if (tloc == 0) y *= QSCALE;                  // fold scale*log2e into Q
                    OT[lr * OTS + oc] = f2u(y);
                }
        }
    }
    __syncthreads();

    // ---- epilogue stage 2: coalesced write-out per 64-col group
#pragma unroll
    for (int g = 0; g < 2; ++g) {
        int a  = ct * 2 + g;        // 64-col group index (0..23)
        int t  = a % 3;
        int bh = b * HH + a / 3;
        if (t != 2) {
            u16* base = qkbuf + ((size_t)((bh * 2 + t) * LL + l0)) * HDM;
#pragma unroll
            for (int it = 0; it < 4; ++it) {
                int idx = it * 256 + tid;       // 0..1023
                int l   = idx >> 3;             // 0..127
                int d8  = (idx & 7) * 8;        // 0..56
                uint4 val = *(const uint4*)&OT[l * OTS + g * 64 + d8];
                *(uint4*)(base + (size_t)l * HDM + d8) = val;
            }
        } else {
            u16* base = vbuf + ((size_t)(bh * HDM)) * LL + l0;
#pragma unroll
            for (int it = 0; it < 4; ++it) {
                int idx = it * 256 + tid;       // 0..1023
                int dd  = idx >> 4;             // 0..63
                int l8  = (idx & 15) * 8;       // 0..120
                u16 tmp[8];
#pragma unroll
                for (int j = 0; j < 8; ++j) tmp[j] = OT[(l8 + j) * OTS + g * 64 + dd];
                uint4 val;
                val.x = (unsigned)tmp[0] | ((unsigned)tmp[1] << 16);
                val.y = (unsigned)tmp[2] | ((unsigned)tmp[3] << 16);
                val.z = (unsigned)tmp[4] | ((unsigned)tmp[5] << 16);
                val.w = (unsigned)tmp[6] | ((unsigned)tmp[7] << 16);
                *(uint4*)(base + (size_t)dd * LL + l8) = val;
            }
        }
    }
#undef OTS
}

// -------------------------------------------------------------------------
// Kernel 2: MFMA flash attention per (b,h) — R13: cross-chunk software
// pipeline. PV for chunk ic-1 issues while chunk ic's S/exp2 runs; P
// A-frags (pa0o/pa1o) carried in registers across iterations; vts is
// triple-buffered (reader lags writer by one chunk; mod-3 keeps buffers
// disjoint, barrier separates). The exp2 -> pts -> pa roundtrip now has a
// full iteration of slack. Static softmax (M=0, exp2 domain). 64-m chunks.
// -------------------------------------------------------------------------
__global__ __launch_bounds__(256) void attn_mfma_kernel(
    const u16* __restrict__ qk,    // [B*H][2][L][64]
    const u16* __restrict__ v,     // [B*H][64][L]
    u16* __restrict__ newv)        // [B][L][512]
{
    __shared__ u16 kts[2][64][64];   // [buf][m][d] swizzled
    __shared__ u16 vts[3][64][64];   // [buf][d][m] swizzled, triple
    __shared__ u16 pts[4][16][76];   // per-wave P [w][m], padded stride

    const int blkid = blockIdx.x;        // bh*32 + wchunk
    const int bh = blkid >> 5;
    const int wc = blkid & 31;
    const int b  = bh >> 3;
    const int h  = bh & 7;
    const int tid  = threadIdx.x;
    const int wave = tid >> 6;
    const int lane = tid & 63;
    const int quad = lane >> 4;
    const int l16  = lane & 15;
    const int e7   = l16 & 7;

    const u16* qbase = qk + ((size_t)(bh * 2 + 0)) * LL * HDM;
    const u16* kbase = qk + ((size_t)(bh * 2 + 1)) * LL * HDM;
    const u16* vbase = v + (size_t)bh * HDM * LL;

    const int w0 = wc * 64 + wave * 16;   // this wave's 16 queries

    short8v qfrag[2];
    qfrag[0] = *(const short8v*)(qbase + (size_t)(w0 + l16) * HDM + quad * 8);
    qfrag[1] = *(const short8v*)(qbase + (size_t)(w0 + l16) * HDM + 32 + quad * 8);

    // ones-column B-frag for row-sum MFMA: B[n=l16][k]=1 iff n==0
    short8v vones;
    {
        short o1 = (l16 == 0) ? (short)0x3F80 : (short)0;
#pragma unroll
        for (int j = 0; j < 8; ++j) vones[j] = o1;
    }

    float4v oacc[4];
#pragma unroll
    for (int dt = 0; dt < 4; ++dt) oacc[dt] = (float4v){0.f, 0.f, 0.f, 0.f};
    float4v lacc = (float4v){0.f, 0.f, 0.f, 0.f};

    // staging: wave stages 16 K rows + 16 V rows per 64-m chunk.
    const int rbase = wave * 16;
    const int lrow  = lane >> 3;          // 0..7
    const int g8    = ((lane & 7) ^ lrow) * 8;
    auto stage = [&](int ic, int kb, int vb2) {
        const int m0 = ic * 64;
#pragma unroll
        for (int j = 0; j < 2; ++j) {
            gld_lds16(kbase + (size_t)(m0 + rbase + j * 8 + lrow) * HDM + g8,
                      &kts[kb][rbase + j * 8][0]);
            gld_lds16(vbase + (size_t)(rbase + j * 8 + lrow) * LL + m0 + g8,
                      &vts[vb2][rbase + j * 8][0]);
        }
    };

    stage(0, 0, 0);

    const int p0 = (quad ^ e7) * 8;         // swizzled chunk, k-half 0
    const int p1 = ((quad + 4) ^ e7) * 8;   // k-half 1

    short8v pa0o, pa1o;                     // P A-frags from previous chunk

    for (int ic = 0; ic < 32; ++ic) {
        const int ck = ic & 1;
        __syncthreads();   // stage(ic) complete (vmcnt drain); prev reads done

        if (ic < 31) stage(ic + 1, 1 - ck, (ic + 1) % 3);

        // S = Q.K^T for chunk ic
        float4v s[4];
#pragma unroll
        for (int mt = 0; mt < 4; ++mt) {
            s[mt] = (float4v){0.f, 0.f, 0.f, 0.f};
            short8v b0 = *(const short8v*)&kts[ck][mt * 16 + l16][p0];
            s[mt] = __builtin_amdgcn_mfma_f32_16x16x32_bf16(qfrag[0], b0, s[mt], 0, 0, 0);
            short8v b1 = *(const short8v*)&kts[ck][mt * 16 + l16][p1];
            s[mt] = __builtin_amdgcn_mfma_f32_16x16x32_bf16(qfrag[1], b1, s[mt], 0, 0, 0);
        }

        // PV for chunk ic-1 (independent of this chunk's S/exp2 — fills
        // the MFMA pipe while exp2 below computes)
        if (ic > 0) {
            const int pv = (ic - 1) % 3;
            lacc = __builtin_amdgcn_mfma_f32_16x16x32_bf16(pa0o, vones, lacc, 0, 0, 0);
            lacc = __builtin_amdgcn_mfma_f32_16x16x32_bf16(pa1o, vones, lacc, 0, 0, 0);
#pragma unroll
            for (int dt = 0; dt < 4; ++dt) {
                short8v v0 = *(const short8v*)&vts[pv][dt * 16 + l16][p0];
                oacc[dt] = __builtin_amdgcn_mfma_f32_16x16x32_bf16(pa0o, v0, oacc[dt], 0, 0, 0);
                short8v v1 = *(const short8v*)&vts[pv][dt * 16 + l16][p1];
                oacc[dt] = __builtin_amdgcn_mfma_f32_16x16x32_bf16(pa1o, v1, oacc[dt], 0, 0, 0);
            }
        }

        // static softmax P = exp2(S) -> pts -> next iteration's A-frags
#pragma unroll
        for (int mt = 0; mt < 4; ++mt)
#pragma unroll
            for (int r = 0; r < 4; ++r)
                pts[wave][quad * 4 + r][mt * 16 + l16] =
                    f2u(__builtin_amdgcn_exp2f(s[mt][r]));

        pa0o = *(const short8v*)&pts[wave][l16][quad * 8];
        pa1o = *(const short8v*)&pts[wave][l16][32 + quad * 8];
    }

    // epilogue: PV for the final chunk (31)
    {
        const int pv = 31 % 3;
        lacc = __builtin_amdgcn_mfma_f32_16x16x32_bf16(pa0o, vones, lacc, 0, 0, 0);
        lacc = __builtin_amdgcn_mfma_f32_16x16x32_bf16(pa1o, vones, lacc, 0, 0, 0);
#pragma unroll
        for (int dt = 0; dt < 4; ++dt) {
            short8v v0 = *(const short8v*)&vts[pv][dt * 16 + l16][p0];
            oacc[dt] = __builtin_amdgcn_mfma_f32_16x16x32_bf16(pa0o, v0, oacc[dt], 0, 0, 0);
            short8v v1 = *(const short8v*)&vts[pv][dt * 16 + l16][p1];
            oacc[dt] = __builtin_amdgcn_mfma_f32_16x16x32_bf16(pa1o, v1, oacc[dt], 0, 0, 0);
        }
    }

    // l_run[r] lives in lane (quad, l16==0) of lacc[r]; broadcast per quad
    float inv[4];
#pragma unroll
    for (int r = 0; r < 4; ++r) {
        float lsum = __shfl(lacc[r], quad * 16);
        inv[r] = 1.f / lsum;
    }
    u16* ob = newv + (size_t)b * LL * 512 + h * 64;
#pragma unroll
    for (int dt = 0; dt < 4; ++dt)
#pragma unroll
        for (int r = 0; r < 4; ++r) {
            int w = w0 + quad * 4 + r;
            ob[(size_t)w * 512 + dt * 16 + l16] = f2u(oacc[dt][r] * inv[r]);
        }
}

// -------------------------------------------------------------------------
// Kernel 3: MFMA FC + swish + residual + layernorm, fused. (unchanged R12)
// -------------------------------------------------------------------------
__global__ __launch_bounds__(256) void fc_ln_mfma_kernel(
    const u16* __restrict__ newv,    // [4096][512] bf16
    const u16* __restrict__ fcw,     // [512][512] bf16
    const u16* __restrict__ fcb,     // [512]
    const u16* __restrict__ xp,      // [B][2050][512] padded bf16
    void* __restrict__ out,          // bf16 or f32 per flag
    const int* __restrict__ flagp)
{
    const int l0 = blockIdx.x * 16;
    const int tid  = threadIdx.x;
    const int wave = tid >> 6;
    const int lane = tid & 63;
    const int quad = lane >> 4;
    const int l16  = lane & 15;
    const int col0 = wave * 128;

    const int bb_ = l0 >> 11;   // batch (16-row tiles never straddle)
    const size_t xbase = ((size_t)(bb_ * 2050 + (l0 & 2047) + 1)) * 512;

    __shared__ float psum[4][16], psq[4][16];

    short8v aF[16];
    const u16* arow = newv + (size_t)(l0 + l16) * 512 + quad * 8;
#pragma unroll
    for (int kc = 0; kc < 16; ++kc)
        aF[kc] = *(const short8v*)(arow + kc * 32);

    float4v acc[8];
#pragma unroll
    for (int nt = 0; nt < 8; ++nt) acc[nt] = (float4v){0.f, 0.f, 0.f, 0.f};

#pragma unroll
    for (int nt = 0; nt < 8; ++nt) {
        const u16* brow = fcw + (size_t)(col0 + nt * 16 + l16) * 512 + quad * 8;
#pragma unroll
        for (int kc = 0; kc < 16; ++kc) {
            short8v bF = *(const short8v*)(brow + kc * 32);
            acc[nt] = __builtin_amdgcn_mfma_f32_16x16x32_bf16(aF[kc], bF, acc[nt], 0, 0, 0);
        }
    }

    float z[8][4];
    float rs[4] = {0.f, 0.f, 0.f, 0.f}, rq[4] = {0.f, 0.f, 0.f, 0.f};
#pragma unroll
    for (int nt = 0; nt < 8; ++nt) {
        int col = col0 + nt * 16 + l16;
        float bb = b2f(fcb[col]);
#pragma unroll
        for (int r = 0; r < 4; ++r) {
            int row = quad * 4 + r;
            float y = acc[nt][r] + bb;
            float sw = y / (1.f + __expf(-y));    // swish
            float xv = b2f(xp[xbase + (size_t)row * 512 + col]);
            float zz = xv * 2.f + sw;
            z[nt][r] = zz;
            rs[r] += zz;
            rq[r] += zz * zz;
        }
    }
#pragma unroll
    for (int msk = 1; msk <= 8; msk <<= 1)
#pragma unroll
        for (int r = 0; r < 4; ++r) {
            rs[r] += __shfl_xor(rs[r], msk);
            rq[r] += __shfl_xor(rq[r], msk);
        }
    if (l16 == 0) {
#pragma unroll
        for (int r = 0; r < 4; ++r) {
            psum[wave][quad * 4 + r] = rs[r];
            psq[wave][quad * 4 + r]  = rq[r];
        }
    }
    __syncthreads();

    float mu[4], inv[4];
#pragma unroll
    for (int r = 0; r < 4; ++r) {
        int row = quad * 4 + r;
        float s = psum[0][row] + psum[1][row] + psum[2][row] + psum[3][row];
        float q = psq[0][row] + psq[1][row] + psq[2][row] + psq[3][row];
        float m = s * (1.f / 512.f);
        float var = q * (1.f / 512.f) - m * m;
        mu[r] = m;
        inv[r] = rsqrtf(var + 1e-5f);
    }

    const int flag = *flagp;
#pragma unroll
    for (int nt = 0; nt < 8; ++nt) {
        int col = col0 + nt * 16 + l16;
#pragma unroll
        for (int r = 0; r < 4; ++r) {
            int row = quad * 4 + r;
            float val = (z[nt][r] - mu[r]) * inv[r];
            if (flag) ((float*)out)[(size_t)(l0 + row) * 512 + col] = val;
            else      ((u16*)out)[(size_t)(l0 + row) * 512 + col] = f2u(val);
        }
    }
}

extern "C" void kernel_launch(void* const* d_in, const int* in_sizes, int n_in,
                              void* d_out, int out_size, void* d_ws, size_t ws_size,
                              hipStream_t stream) {
    (void)in_sizes; (void)n_in; (void)out_size; (void)ws_size;

    char* ws = (char*)d_ws;
    int* flag = (int*)ws;
    u16* xp   = (u16*)(ws + 256);        // [2][2050][512] 4,198,400 B -> ends 4,198,656
    u16* wtc  = (u16*)(ws + 4198656);    // [1536][1536] 4,718,592 B  -> ends 8,917,248
    u16* bc   = (u16*)(ws + 8917248);    // 3,072 B  -> ends 8,920,320
    u16* fwc  = (u16*)(ws + 8920320);    // 524,288 B -> ends 9,444,608
    u16* fbc  = (u16*)(ws + 9444608);    // 1,024 B  -> ends 9,445,632
    u16* qkb  = (u16*)(ws + 9445632);    // [16][2][2048][64] = 8 MB -> ends 17,834,240
    u16* vb   = (u16*)(ws + 17834240);   // [16][64][2048]    = 4 MB -> ends 22,028,544
    u16* nvc  = (u16*)(ws + 22028544);   // [2][2048][512]    = 4 MB -> ends 26,222,848

    detect_kernel<<<dim3(1), dim3(64), 0, stream>>>((const u16*)d_in[0], flag);

    convert_xpad_kernel<<<dim3((BB * LL * 64 + 255) / 256), dim3(256), 0, stream>>>(d_in[0], xp, flag);
    convw_kernel<<<dim3(1152), dim3(256), 0, stream>>>(d_in[1], wtc, flag);
    convert_small_kernel<<<dim3((BN / 8 + FWN / 8 + FBN / 8 + 255) / 256), dim3(256), 0, stream>>>(
        d_in[2], d_in[3], d_in[4], bc, fwc, fbc, flag);

    conv_mfma_kernel<<<dim3(32 * 12), dim3(256), 0, stream>>>(xp, wtc, bc, qkb, vb);
    attn_mfma_kernel<<<dim3(BB * HH * (LL / 64)), dim3(256), 0, stream>>>(qkb, vb, nvc);
    fc_ln_mfma_kernel<<<dim3(256), dim3(256), 0, stream>>>(nvc, fwc, fbc, xp, d_out, flag);
}

// Round 14
// 174.846 us; speedup vs baseline: 1.0319x; 1.0319x over previous
//
#include <hip/hip_runtime.h>
#include <hip/hip_bf16.h>

// Problem constants
#define BB 2
#define LL 2048
#define DD 512
#define HH 8
#define HDM 64
#define SCALE 0.022097086912079608f    // 1/sqrt(2048)
#define QSCALE 0.03187935766f          // SCALE * log2(e)  (exp2-domain softmax)

typedef __hip_bfloat16 bf16;
typedef unsigned short u16;
typedef __attribute__((ext_vector_type(8))) short short8v;   // 8 bf16 (4 VGPRs)
typedef __attribute__((ext_vector_type(4))) float float4v;   // 4 fp32 acc

// Input element counts
#define XN  2097152    // 2*2048*512
#define WN  2359296    // 1536*512*3
#define BN  1536
#define FWN 262144     // 512*512
#define FBN 512

__device__ __forceinline__ float b2f(u16 u) {
    return __uint_as_float(((unsigned int)u) << 16);
}
__device__ __forceinline__ u16 f2u(float f) {
    bf16 h = __float2bfloat16(f);
    u16 r;
    __builtin_memcpy(&r, &h, 2);
    return r;
}
__device__ __forceinline__ uint4 pack8(const float* f) {
    uint4 p;
    p.x = (unsigned)f2u(f[0]) | ((unsigned)f2u(f[1]) << 16);
    p.y = (unsigned)f2u(f[2]) | ((unsigned)f2u(f[3]) << 16);
    p.z = (unsigned)f2u(f[4]) | ((unsigned)f2u(f[5]) << 16);
    p.w = (unsigned)f2u(f[6]) | ((unsigned)f2u(f[7]) << 16);
    return p;
}

// async 16-B global -> LDS copy (lds dest = wave-uniform base + lane*16)
__device__ __forceinline__ void gld_lds16(const u16* g, u16* l) {
    __builtin_amdgcn_global_load_lds(
        (const __attribute__((address_space(1))) unsigned int*)g,
        (__attribute__((address_space(3))) unsigned int*)l, 16, 0, 0);
}

// -------------------------------------------------------------------------
// Kernel 0: dtype detect (f32 vs bf16 inputs). See R1 notes.
// -------------------------------------------------------------------------
__global__ void detect_kernel(const u16* __restrict__ x, int* __restrict__ flag) {
    int bad = 0;
    for (int i = threadIdx.x; i < 256; i += 64) {
        float v = b2f(x[i]);
        if (!(fabsf(v) < 100.f)) bad = 1;   // catches NaN too
    }
    unsigned long long m = __ballot(bad);
    if (threadIdx.x == 0) *flag = (m != 0ull) ? 1 : 0;
}

__device__ __forceinline__ void conv8(const void* src, u16* dst, size_t i, int flag) {
    if (flag) {
        const float* s = (const float*)src;
        float f[8];
        float4 a = *(const float4*)(s + i);
        float4 b = *(const float4*)(s + i + 4);
        f[0] = a.x; f[1] = a.y; f[2] = a.z; f[3] = a.w;
        f[4] = b.x; f[5] = b.y; f[6] = b.z; f[7] = b.w;
        *(uint4*)(dst + i) = pack8(f);
    } else {
        *(uint4*)(dst + i) = *(const uint4*)((const u16*)src + i);
    }
}

// -------------------------------------------------------------------------
// Kernel 0a: fused small converts: cnn_b (1536) + fc_w (262144) + fc_b (512)
// -------------------------------------------------------------------------
__global__ __launch_bounds__(256) void convert_small_kernel(
    const void* __restrict__ bsrc, const void* __restrict__ fwsrc,
    const void* __restrict__ fbsrc,
    u16* __restrict__ bc, u16* __restrict__ fwc, u16* __restrict__ fbc,
    const int* __restrict__ flagp)
{
    const int flag = *flagp;
    int o = blockIdx.x * 256 + threadIdx.x;          // octet id
    if (o < BN / 8) {
        conv8(bsrc, bc, (size_t)o * 8, flag);
    } else if (o < BN / 8 + FWN / 8) {
        conv8(fwsrc, fwc, (size_t)(o - BN / 8) * 8, flag);
    } else if (o < BN / 8 + FWN / 8 + FBN / 8) {
        conv8(fbsrc, fbc, (size_t)(o - BN / 8 - FWN / 8) * 8, flag);
    }
}

// -------------------------------------------------------------------------
// Kernel 0b': x -> zero-guard-padded xp[B][2050][512]; threads 0..255 also
// zero the guard rows (merged zeropad).
// -------------------------------------------------------------------------
__global__ __launch_bounds__(256) void convert_xpad_kernel(
    const void* __restrict__ src, u16* __restrict__ xp,
    const int* __restrict__ flagp)
{
    const int flag = *flagp;
    int idx = blockIdx.x * 256 + threadIdx.x;     // octet id, < 2*2048*64
    if (idx < 256) {
        int b2  = idx >> 7;
        int r2  = (idx >> 6) & 1;
        int c82 = (idx & 63) * 8;
        size_t off = ((size_t)(b2 * 2050 + (r2 ? 2049 : 0))) * 512 + c82;
        uint4 z = {0u, 0u, 0u, 0u};
        *(uint4*)(xp + off) = z;
    }
    if (idx >= BB * LL * 64) return;
    int b   = idx / (LL * 64);
    int rem = idx - b * (LL * 64);
    int l   = rem >> 6;
    int c8  = (rem & 63) * 8;
    size_t si = ((size_t)(b * LL + l)) * 512 + c8;
    size_t di = ((size_t)(b * 2050 + l + 1)) * 512 + c8;
    if (flag) {
        const float* s = (const float*)src;
        float f[8];
        float4 a = *(const float4*)(s + si);
        float4 bq = *(const float4*)(s + si + 4);
        f[0] = a.x; f[1] = a.y; f[2] = a.z; f[3] = a.w;
        f[4] = bq.x; f[5] = bq.y; f[6] = bq.z; f[7] = bq.w;
        *(uint4*)(xp + di) = pack8(f);
    } else {
        *(uint4*)(xp + di) = *(const uint4*)((const u16*)src + si);
    }
}

// -------------------------------------------------------------------------
// Kernel 0c: cnn_w canonicalize + transpose [o][i][k] -> [o][k*512+i].
// -------------------------------------------------------------------------
__global__ __launch_bounds__(256) void convw_kernel(
    const void* __restrict__ src, u16* __restrict__ wt,
    const int* __restrict__ flagp)
{
    const int flag = *flagp;
    int idx = blockIdx.x * 256 + threadIdx.x;   // < 1536*3*64
    int i8  = idx & 63;
    int rem = idx >> 6;
    int k   = rem % 3;
    int o   = rem / 3;
    float f[8];
    if (flag) {
        const float* s = (const float*)src;
#pragma unroll
        for (int j = 0; j < 8; ++j) f[j] = s[(size_t)o * 1536 + (i8 * 8 + j) * 3 + k];
    } else {
        const u16* s = (const u16*)src;
#pragma unroll
        for (int j = 0; j < 8; ++j) f[j] = b2f(s[(size_t)o * 1536 + (i8 * 8 + j) * 3 + k]);
    }
    *(uint4*)(wt + (size_t)o * 1536 + k * 512 + i8 * 8) = pack8(f);
}

// -------------------------------------------------------------------------
// Kernel 1: conv GEMM — R14: 128x64 tiles, 768 blocks = 3/CU balanced.
// m97-style K-loop (global_load_lds, XOR swizzle, 1 barrier/chunk).
// Each block's 64-col group = exactly one (bh,t): epilogue t is uniform.
// LDS 48 KB -> 3 blocks/CU co-resident.
// -------------------------------------------------------------------------
__global__ __launch_bounds__(256) void conv_mfma_kernel(
    const u16* __restrict__ xp,     // [B][2050][512] padded bf16
    const u16* __restrict__ wt,     // [1536][1536] = [o][k*512+i]
    const u16* __restrict__ bias,   // [1536]
    u16* __restrict__ qkbuf,        // [B*H][2][L][64]
    u16* __restrict__ vbuf)         // [B*H][64][L]
{
    __shared__ u16 smem[24576];     // 49152 B
    u16* Asb = smem;                // [2][128][64] unpadded, swizzled
    u16* Bsb = smem + 2 * 128 * 64; // [2][64][64]  unpadded, swizzled
#define OTS 140
    u16* OT  = smem;                // [128][140] aliased after final sync

    const int blk = blockIdx.x;          // rt*24 + ct
    const int rt = blk / 24;
    const int ct = blk - rt * 24;        // 64-col group id (0..23)
    const int b  = rt >> 4;
    const int l0 = (rt & 15) * 128;
    const int tid  = threadIdx.x;
    const int wave = tid >> 6;
    const int lane = tid & 63;
    const int quad = lane >> 4;
    const int l16  = lane & 15;
    const int e7   = l16 & 7;
    const int wx = wave & 1;             // n half (32 cols)
    const int wy = wave >> 1;            // m half (64 rows)

    float4v acc[4][2];
#pragma unroll
    for (int mt = 0; mt < 4; ++mt)
#pragma unroll
        for (int nt = 0; nt < 2; ++nt) acc[mt][nt] = (float4v){0.f, 0.f, 0.f, 0.f};

    const int rowW = wave * 32;          // A staging rows
    const int rowB = wave * 16;          // B staging rows
    const int lrow = lane >> 3;          // 0..7
    const int g8   = (((lane & 7) ^ lrow)) * 8;
    auto stage = [&](int kc, int buf) {
        const int slab = kc >> 3;                // conv tap k (0..2)
        const int i0   = (kc & 7) * 64;          // input-channel slice
        const u16* ga = xp + ((size_t)(b * 2050 + l0 + rowW + slab + lrow)) * 512 + i0 + g8;
        const u16* gb = wt + ((size_t)(ct * 64 + rowB + lrow)) * 1536 + kc * 64 + g8;
        u16* la = Asb + (size_t)(buf * 128 + rowW) * 64;
        u16* lb = Bsb + (size_t)(buf * 64 + rowB) * 64;
#pragma unroll
        for (int j = 0; j < 4; ++j)
            gld_lds16(ga + (size_t)(j * 8) * 512,  la + (j * 8) * 64);
#pragma unroll
        for (int j = 0; j < 2; ++j)
            gld_lds16(gb + (size_t)(j * 8) * 1536, lb + (j * 8) * 64);
    };

    stage(0, 0);

    for (int kc = 0; kc < 24; ++kc) {
        const int cur = kc & 1;
        __syncthreads();   // drains vmcnt -> chunk kc staged; prev reads done

        if (kc < 23) stage(kc + 1, 1 - cur);

#pragma unroll
        for (int half = 0; half < 2; ++half) {
            const int p = ((half * 4 + quad) ^ e7) * 8;   // swizzled chunk
            short8v aF[4], bF[2];
#pragma unroll
            for (int mt = 0; mt < 4; ++mt)
                aF[mt] = *(const short8v*)&Asb[(size_t)(cur * 128 + wy * 64 + mt * 16 + l16) * 64 + p];
#pragma unroll
            for (int nt = 0; nt < 2; ++nt)
                bF[nt] = *(const short8v*)&Bsb[(size_t)(cur * 64 + wx * 32 + nt * 16 + l16) * 64 + p];
#pragma unroll
            for (int mt = 0; mt < 4; ++mt)
#pragma unroll
                for (int nt = 0; nt < 2; ++nt)
                    acc[mt][nt] = __builtin_amdgcn_mfma_f32_16x16x32_bf16(
                        aF[mt], bF[nt], acc[mt][nt], 0, 0, 0);
        }
    }

    const int t  = ct % 3;               // block-uniform output kind
    const int bh = b * HH + ct / 3;

    // ---- epilogue stage 1: bias+swish(+QSCALE) in regs -> OT [128 l][64 o]
    __syncthreads();   // all LDS tile reads done; safe to alias as OT
#pragma unroll
    for (int nt = 0; nt < 2; ++nt) {
        int oc = wx * 32 + nt * 16 + l16;           // tile-local col (0..63)
        float bb = b2f(bias[ct * 64 + oc]);
#pragma unroll
        for (int mt = 0; mt < 4; ++mt)
#pragma unroll
            for (int r = 0; r < 4; ++r) {
                int lr = wy * 64 + mt * 16 + quad * 4 + r;   // tile-local row
                float y = acc[mt][nt][r] + bb;
                y = y / (1.f + __expf(-y));                  // swish
                if (t == 0) y *= QSCALE;                     // fold scale*log2e into Q
                OT[lr * OTS + oc] = f2u(y);
            }
    }
    __syncthreads();

    // ---- epilogue stage 2: coalesced write-out (single 64-col group)
    if (t != 2) {
        u16* base = qkbuf + ((size_t)((bh * 2 + t) * LL + l0)) * HDM;
#pragma unroll
        for (int it = 0; it < 4; ++it) {
            int idx = it * 256 + tid;       // 0..1023
            int l   = idx >> 3;             // 0..127
            int d8  = (idx & 7) * 8;        // 0..56
            uint4 val = *(const uint4*)&OT[l * OTS + d8];
            *(uint4*)(base + (size_t)l * HDM + d8) = val;
        }
    } else {
        u16* base = vbuf + ((size_t)(bh * HDM)) * LL + l0;
#pragma unroll
        for (int it = 0; it < 4; ++it) {
            int idx = it * 256 + tid;       // 0..1023
            int dd  = idx >> 4;             // 0..63
            int l8  = (idx & 15) * 8;       // 0..120
            u16 tmp[8];
#pragma unroll
            for (int j = 0; j < 8; ++j) tmp[j] = OT[(l8 + j) * OTS + dd];
            uint4 val;
            val.x = (unsigned)tmp[0] | ((unsigned)tmp[1] << 16);
            val.y = (unsigned)tmp[2] | ((unsigned)tmp[3] << 16);
            val.z = (unsigned)tmp[4] | ((unsigned)tmp[5] << 16);
            val.w = (unsigned)tmp[6] | ((unsigned)tmp[7] << 16);
            *(uint4*)(base + (size_t)dd * LL + l8) = val;
        }
    }
#undef OTS
}

// -------------------------------------------------------------------------
// Kernel 2: MFMA flash attention per (b,h) — verified R12 form: m-chunk=128,
// static softmax (M=0, exp2 domain, QSCALE pre-folded), barriers 16, row-sum
// via ones-column MFMA, zero bank conflicts.
// -------------------------------------------------------------------------
__global__ __launch_bounds__(256) void attn_mfma_kernel(
    const u16* __restrict__ qk,    // [B*H][2][L][64]
    const u16* __restrict__ v,     // [B*H][64][L]
    u16* __restrict__ newv)        // [B][L][512]
{
    __shared__ u16 kts[2][128][64];  // [buf][m][d] swizzled
    __shared__ u16 vts[2][64][128];  // [buf][d][m] swizzled
    __shared__ u16 pts[4][16][76];   // per-wave P [w][m], padded stride

    const int blkid = blockIdx.x;        // bh*32 + wchunk
    const int bh = blkid >> 5;
    const int wc = blkid & 31;
    const int b  = bh >> 3;
    const int h  = bh & 7;
    const int tid  = threadIdx.x;
    const int wave = tid >> 6;
    const int lane = tid & 63;
    const int quad = lane >> 4;
    const int l16  = lane & 15;
    const int e7   = l16 & 7;

    const u16* qbase = qk + ((size_t)(bh * 2 + 0)) * LL * HDM;
    const u16* kbase = qk + ((size_t)(bh * 2 + 1)) * LL * HDM;
    const u16* vbase = v + (size_t)bh * HDM * LL;

    const int w0 = wc * 64 + wave * 16;   // this wave's 16 queries

    short8v qfrag[2];
    qfrag[0] = *(const short8v*)(qbase + (size_t)(w0 + l16) * HDM + quad * 8);
    qfrag[1] = *(const short8v*)(qbase + (size_t)(w0 + l16) * HDM + 32 + quad * 8);

    // ones-column B-frag for row-sum MFMA: B[n=l16][k]=1 iff n==0
    short8v vones;
    {
        short o1 = (l16 == 0) ? (short)0x3F80 : (short)0;
#pragma unroll
        for (int j = 0; j < 8; ++j) vones[j] = o1;
    }

    float4v oacc[4];
#pragma unroll
    for (int dt = 0; dt < 4; ++dt) oacc[dt] = (float4v){0.f, 0.f, 0.f, 0.f};
    float4v lacc = (float4v){0.f, 0.f, 0.f, 0.f};

    // staging: wave stages 32 K rows (4 gld x 8 rows) + 16 V rows (4 gld x
    // 4 rows of 128) per 128-m chunk.
    const int rbK   = wave * 32;
    const int lrowK = lane >> 3;          // 0..7
    const int gK    = ((lane & 7) ^ lrowK) * 8;
    const int rbV   = wave * 16;
    const int lrowV = lane >> 4;          // 0..3
    auto stage = [&](int ic, int buf) {
        const int m0 = ic * 128;
#pragma unroll
        for (int j = 0; j < 4; ++j) {
            gld_lds16(kbase + (size_t)(m0 + rbK + j * 8 + lrowK) * HDM + gK,
                      &kts[buf][rbK + j * 8][0]);
            const int vrow = j * 4 + lrowV;           // row&15 (rbV mult of 16)
            gld_lds16(vbase + (size_t)(rbV + vrow) * LL + m0 + (((lane & 15) ^ vrow) * 8),
                      &vts[buf][rbV + j * 4][0]);
        }
    };

    stage(0, 0);

    for (int ic = 0; ic < 16; ++ic) {
        const int cur = ic & 1;
        __syncthreads();   // drains vmcnt -> chunk ic staged; prev reads done

        if (ic < 15) stage(ic + 1, 1 - cur);

        // S = Q.K^T for all 8 m-tiles of this 128-m chunk
        float4v s[8];
#pragma unroll
        for (int mt = 0; mt < 8; ++mt) {
            s[mt] = (float4v){0.f, 0.f, 0.f, 0.f};
            short8v b0 = *(const short8v*)&kts[cur][mt * 16 + l16][((quad) ^ e7) * 8];
            s[mt] = __builtin_amdgcn_mfma_f32_16x16x32_bf16(qfrag[0], b0, s[mt], 0, 0, 0);
            short8v b1 = *(const short8v*)&kts[cur][mt * 16 + l16][((quad + 4) ^ e7) * 8];
            s[mt] = __builtin_amdgcn_mfma_f32_16x16x32_bf16(qfrag[1], b1, s[mt], 0, 0, 0);
        }

        // per 64-m half: P = exp2(S) -> pts -> A-frags -> lacc/oacc MFMA
#pragma unroll
        for (int g = 0; g < 2; ++g) {
#pragma unroll
            for (int mt4 = 0; mt4 < 4; ++mt4)
#pragma unroll
                for (int r = 0; r < 4; ++r)
                    pts[wave][quad * 4 + r][mt4 * 16 + l16] =
                        f2u(__builtin_amdgcn_exp2f(s[g * 4 + mt4][r]));

            short8v pa0 = *(const short8v*)&pts[wave][l16][quad * 8];
            short8v pa1 = *(const short8v*)&pts[wave][l16][32 + quad * 8];

            lacc = __builtin_amdgcn_mfma_f32_16x16x32_bf16(pa0, vones, lacc, 0, 0, 0);
            lacc = __builtin_amdgcn_mfma_f32_16x16x32_bf16(pa1, vones, lacc, 0, 0, 0);

#pragma unroll
            for (int dt = 0; dt < 4; ++dt) {
                short8v v0 = *(const short8v*)&vts[cur][dt * 16 + l16][((g * 8 + quad) ^ l16) * 8];
                oacc[dt] = __builtin_amdgcn_mfma_f32_16x16x32_bf16(pa0, v0, oacc[dt], 0, 0, 0);
                short8v v1 = *(const short8v*)&vts[cur][dt * 16 + l16][((g * 8 + 4 + quad) ^ l16) * 8];
                oacc[dt] = __builtin_amdgcn_mfma_f32_16x16x32_bf16(pa1, v1, oacc[dt], 0, 0, 0);
            }
        }
    }

    // l_run[r] lives in lane (quad, l16==0) of lacc[r]; broadcast per quad
    float inv[4];
#pragma unroll
    for (int r = 0; r < 4; ++r) {
        float lsum = __shfl(lacc[r], quad * 16);
        inv[r] = 1.f / lsum;
    }
    u16* ob = newv + (size_t)b * LL * 512 + h * 64;
#pragma unroll
    for (int dt = 0; dt < 4; ++dt)
#pragma unroll
        for (int r = 0; r < 4; ++r) {
            int w = w0 + quad * 4 + r;
            ob[(size_t)w * 512 + dt * 16 + l16] = f2u(oacc[dt][r] * inv[r]);
        }
}

// -------------------------------------------------------------------------
// Kernel 3: MFMA FC + swish + residual + layernorm, fused. (unchanged R12)
// -------------------------------------------------------------------------
__global__ __launch_bounds__(256) void fc_ln_mfma_kernel(
    const u16* __restrict__ newv,    // [4096][512] bf16
    const u16* __restrict__ fcw,     // [512][512] bf16
    const u16* __restrict__ fcb,     // [512]
    const u16* __restrict__ xp,      // [B][2050][512] padded bf16
    void* __restrict__ out,          // bf16 or f32 per flag
    const int* __restrict__ flagp)
{
    const int l0 = blockIdx.x * 16;
    const int tid  = threadIdx.x;
    const int wave = tid >> 6;
    const int lane = tid & 63;
    const int quad = lane >> 4;
    const int l16  = lane & 15;
    const int col0 = wave * 128;

    const int bb_ = l0 >> 11;   // batch (16-row tiles never straddle)
    const size_t xbase = ((size_t)(bb_ * 2050 + (l0 & 2047) + 1)) * 512;

    __shared__ float psum[4][16], psq[4][16];

    short8v aF[16];
    const u16* arow = newv + (size_t)(l0 + l16) * 512 + quad * 8;
#pragma unroll
    for (int kc = 0; kc < 16; ++kc)
        aF[kc] = *(const short8v*)(arow + kc * 32);

    float4v acc[8];
#pragma unroll
    for (int nt = 0; nt < 8; ++nt) acc[nt] = (float4v){0.f, 0.f, 0.f, 0.f};

#pragma unroll
    for (int nt = 0; nt < 8; ++nt) {
        const u16* brow = fcw + (size_t)(col0 + nt * 16 + l16) * 512 + quad * 8;
#pragma unroll
        for (int kc = 0; kc < 16; ++kc) {
            short8v bF = *(const short8v*)(brow + kc * 32);
            acc[nt] = __builtin_amdgcn_mfma_f32_16x16x32_bf16(aF[kc], bF, acc[nt], 0, 0, 0);
        }
    }

    float z[8][4];
    float rs[4] = {0.f, 0.f, 0.f, 0.f}, rq[4] = {0.f, 0.f, 0.f, 0.f};
#pragma unroll
    for (int nt = 0; nt < 8; ++nt) {
        int col = col0 + nt * 16 + l16;
        float bb = b2f(fcb[col]);
#pragma unroll
        for (int r = 0; r < 4; ++r) {
            int row = quad * 4 + r;
            float y = acc[nt][r] + bb;
            float sw = y / (1.f + __expf(-y));    // swish
            float xv = b2f(xp[xbase + (size_t)row * 512 + col]);
            float zz = xv * 2.f + sw;
            z[nt][r] = zz;
            rs[r] += zz;
            rq[r] += zz * zz;
        }
    }
#pragma unroll
    for (int msk = 1; msk <= 8; msk <<= 1)
#pragma unroll
        for (int r = 0; r < 4; ++r) {
            rs[r] += __shfl_xor(rs[r], msk);
            rq[r] += __shfl_xor(rq[r], msk);
        }
    if (l16 == 0) {
#pragma unroll
        for (int r = 0; r < 4; ++r) {
            psum[wave][quad * 4 + r] = rs[r];
            psq[wave][quad * 4 + r]  = rq[r];
        }
    }
    __syncthreads();

    float mu[4], inv[4];
#pragma unroll
    for (int r = 0; r < 4; ++r) {
        int row = quad * 4 + r;
        float s = psum[0][row] + psum[1][row] + psum[2][row] + psum[3][row];
        float q = psq[0][row] + psq[1][row] + psq[2][row] + psq[3][row];
        float m = s * (1.f / 512.f);
        float var = q * (1.f / 512.f) - m * m;
        mu[r] = m;
        inv[r] = rsqrtf(var + 1e-5f);
    }

    const int flag = *flagp;
#pragma unroll
    for (int nt = 0; nt < 8; ++nt) {
        int col = col0 + nt * 16 + l16;
#pragma unroll
        for (int r = 0; r < 4; ++r) {
            int row = quad * 4 + r;
            float val = (z[nt][r] - mu[r]) * inv[r];
            if (flag) ((float*)out)[(size_t)(l0 + row) * 512 + col] = val;
            else      ((u16*)out)[(size_t)(l0 + row) * 512 + col] = f2u(val);
        }
    }
}

extern "C" void kernel_launch(void* const* d_in, const int* in_sizes, int n_in,
                              void* d_out, int out_size, void* d_ws, size_t ws_size,
                              hipStream_t stream) {
    (void)in_sizes; (void)n_in; (void)out_size; (void)ws_size;

    char* ws = (char*)d_ws;
    int* flag = (int*)ws;
    u16* xp   = (u16*)(ws + 256);        // [2][2050][512] 4,198,400 B -> ends 4,198,656
    u16* wtc  = (u16*)(ws + 4198656);    // [1536][1536] 4,718,592 B  -> ends 8,917,248
    u16* bc   = (u16*)(ws + 8917248);    // 3,072 B  -> ends 8,920,320
    u16* fwc  = (u16*)(ws + 8920320);    // 524,288 B -> ends 9,444,608
    u16* fbc  = (u16*)(ws + 9444608);    // 1,024 B  -> ends 9,445,632
    u16* qkb  = (u16*)(ws + 9445632);    // [16][2][2048][64] = 8 MB -> ends 17,834,240
    u16* vb   = (u16*)(ws + 17834240);   // [16][64][2048]    = 4 MB -> ends 22,028,544
    u16* nvc  = (u16*)(ws + 22028544);   // [2][2048][512]    = 4 MB -> ends 26,222,848

    detect_kernel<<<dim3(1), dim3(64), 0, stream>>>((const u16*)d_in[0], flag);

    convert_xpad_kernel<<<dim3((BB * LL * 64 + 255) / 256), dim3(256), 0, stream>>>(d_in[0], xp, flag);
    convw_kernel<<<dim3(1152), dim3(256), 0, stream>>>(d_in[1], wtc, flag);
    convert_small_kernel<<<dim3((BN / 8 + FWN / 8 + FBN / 8 + 255) / 256), dim3(256), 0, stream>>>(
        d_in[2], d_in[3], d_in[4], bc, fwc, fbc, flag);

    conv_mfma_kernel<<<dim3(32 * 24), dim3(256), 0, stream>>>(xp, wtc, bc, qkb, vb);
    attn_mfma_kernel<<<dim3(BB * HH * (LL / 64)), dim3(256), 0, stream>>>(qkb, vb, nvc);
    fc_ln_mfma_kernel<<<dim3(256), dim3(256), 0, stream>>>(nvc, fwc, fbc, xp, d_out, flag);
}

// Round 16
// 170.076 us; speedup vs baseline: 1.0609x; 1.0280x over previous
//
#include <hip/hip_runtime.h>
#include <hip/hip_bf16.h>

// Problem constants
#define BB 2
#define LL 2048
#define DD 512
#define HH 8
#define HDM 64
#define SCALE 0.022097086912079608f    // 1/sqrt(2048)
#define QSCALE 0.03187935766f          // SCALE * log2(e)  (exp2-domain softmax)

typedef __hip_bfloat16 bf16;
typedef unsigned short u16;
typedef __attribute__((ext_vector_type(8))) short short8v;   // 8 bf16 (4 VGPRs)
typedef __attribute__((ext_vector_type(4))) float float4v;   // 4 fp32 acc

// Input element counts
#define XN  2097152    // 2*2048*512
#define WN  2359296    // 1536*512*3
#define BN  1536
#define FWN 262144     // 512*512
#define FBN 512

__device__ __forceinline__ float b2f(u16 u) {
    return __uint_as_float(((unsigned int)u) << 16);
}
__device__ __forceinline__ u16 f2u(float f) {
    bf16 h = __float2bfloat16(f);
    u16 r;
    __builtin_memcpy(&r, &h, 2);
    return r;
}
__device__ __forceinline__ uint4 pack8(const float* f) {
    uint4 p;
    p.x = (unsigned)f2u(f[0]) | ((unsigned)f2u(f[1]) << 16);
    p.y = (unsigned)f2u(f[2]) | ((unsigned)f2u(f[3]) << 16);
    p.z = (unsigned)f2u(f[4]) | ((unsigned)f2u(f[5]) << 16);
    p.w = (unsigned)f2u(f[6]) | ((unsigned)f2u(f[7]) << 16);
    return p;
}

// async 16-B global -> LDS copy (lds dest = wave-uniform base + lane*16)
__device__ __forceinline__ void gld_lds16(const u16* g, u16* l) {
    __builtin_amdgcn_global_load_lds(
        (const __attribute__((address_space(1))) unsigned int*)g,
        (__attribute__((address_space(3))) unsigned int*)l, 16, 0, 0);
}

// -------------------------------------------------------------------------
// Kernel 0: dtype detect (f32 vs bf16 inputs). See R1 notes.
// -------------------------------------------------------------------------
__global__ void detect_kernel(const u16* __restrict__ x, int* __restrict__ flag) {
    int bad = 0;
    for (int i = threadIdx.x; i < 256; i += 64) {
        float v = b2f(x[i]);
        if (!(fabsf(v) < 100.f)) bad = 1;   // catches NaN too
    }
    unsigned long long m = __ballot(bad);
    if (threadIdx.x == 0) *flag = (m != 0ull) ? 1 : 0;
}

__device__ __forceinline__ void conv8(const void* src, u16* dst, size_t i, int flag) {
    if (flag) {
        const float* s = (const float*)src;
        float f[8];
        float4 a = *(const float4*)(s + i);
        float4 b = *(const float4*)(s + i + 4);
        f[0] = a.x; f[1] = a.y; f[2] = a.z; f[3] = a.w;
        f[4] = b.x; f[5] = b.y; f[6] = b.z; f[7] = b.w;
        *(uint4*)(dst + i) = pack8(f);
    } else {
        *(uint4*)(dst + i) = *(const uint4*)((const u16*)src + i);
    }
}

// -------------------------------------------------------------------------
// Kernel 0': unified prep — one launch, block-range branch:
//   [0,1024)    : x -> zero-guard-padded xp[B][2050][512] (+ guard rows)
//                 (262,144 octets = 1024 blocks — R15 bug: had 512)
//   [1024,2176) : cnn_w canonicalize + transpose [o][i][k]->[o][k*512+i]
//   [2176,2305) : cnn_b + fc_w + fc_b converts
// -------------------------------------------------------------------------
__global__ __launch_bounds__(256) void prep_kernel(
    const void* __restrict__ xsrc, const void* __restrict__ wsrc,
    const void* __restrict__ bsrc, const void* __restrict__ fwsrc,
    const void* __restrict__ fbsrc,
    u16* __restrict__ xp, u16* __restrict__ wt,
    u16* __restrict__ bc, u16* __restrict__ fwc, u16* __restrict__ fbc,
    const int* __restrict__ flagp)
{
    const int flag = *flagp;
    const int bid = blockIdx.x;

    if (bid < 1024) {
        // ---- xpad ----
        int idx = bid * 256 + threadIdx.x;           // octet id, < 2*2048*64
        if (idx < 256) {
            int b2  = idx >> 7;
            int r2  = (idx >> 6) & 1;
            int c82 = (idx & 63) * 8;
            size_t off = ((size_t)(b2 * 2050 + (r2 ? 2049 : 0))) * 512 + c82;
            uint4 z = {0u, 0u, 0u, 0u};
            *(uint4*)(xp + off) = z;
        }
        int b   = idx / (LL * 64);
        int rem = idx - b * (LL * 64);
        int l   = rem >> 6;
        int c8  = (rem & 63) * 8;
        size_t si = ((size_t)(b * LL + l)) * 512 + c8;
        size_t di = ((size_t)(b * 2050 + l + 1)) * 512 + c8;
        if (flag) {
            const float* s = (const float*)xsrc;
            float f[8];
            float4 a = *(const float4*)(s + si);
            float4 bq = *(const float4*)(s + si + 4);
            f[0] = a.x; f[1] = a.y; f[2] = a.z; f[3] = a.w;
            f[4] = bq.x; f[5] = bq.y; f[6] = bq.z; f[7] = bq.w;
            *(uint4*)(xp + di) = pack8(f);
        } else {
            *(uint4*)(xp + di) = *(const uint4*)((const u16*)xsrc + si);
        }
    } else if (bid < 2176) {
        // ---- convw ----
        int idx = (bid - 1024) * 256 + threadIdx.x;  // < 1536*3*64
        int i8  = idx & 63;
        int rem = idx >> 6;
        int k   = rem % 3;
        int o   = rem / 3;
        float f[8];
        if (flag) {
            const float* s = (const float*)wsrc;
#pragma unroll
            for (int j = 0; j < 8; ++j) f[j] = s[(size_t)o * 1536 + (i8 * 8 + j) * 3 + k];
        } else {
            const u16* s = (const u16*)wsrc;
#pragma unroll
            for (int j = 0; j < 8; ++j) f[j] = b2f(s[(size_t)o * 1536 + (i8 * 8 + j) * 3 + k]);
        }
        *(uint4*)(wt + (size_t)o * 1536 + k * 512 + i8 * 8) = pack8(f);
    } else {
        // ---- small converts ----
        int o = (bid - 2176) * 256 + threadIdx.x;    // octet id
        if (o < BN / 8) {
            conv8(bsrc, bc, (size_t)o * 8, flag);
        } else if (o < BN / 8 + FWN / 8) {
            conv8(fwsrc, fwc, (size_t)(o - BN / 8) * 8, flag);
        } else if (o < BN / 8 + FWN / 8 + FBN / 8) {
            conv8(fbsrc, fbc, (size_t)(o - BN / 8 - FWN / 8) * 8, flag);
        }
    }
}

// -------------------------------------------------------------------------
// Kernel 1: conv GEMM — R12-verified form: 128x128 tiles, 384 blocks,
// m97-style K-loop (global_load_lds 16B, XOR bank swizzle, 1 barrier/chunk),
// LDS-transpose epilogue (coalesced qkbuf/vbuf writes), QSCALE fold into Q.
// -------------------------------------------------------------------------
__global__ __launch_bounds__(256) void conv_mfma_kernel(
    const u16* __restrict__ xp,     // [B][2050][512] padded bf16
    const u16* __restrict__ wt,     // [1536][1536] = [o][k*512+i]
    const u16* __restrict__ bias,   // [1536]
    u16* __restrict__ qkbuf,        // [B*H][2][L][64]
    u16* __restrict__ vbuf)         // [B*H][64][L]
{
    __shared__ u16 smem[32768];     // 65536 B
    u16* Asb = smem;                // [2][128][64] unpadded, swizzled
    u16* Bsb = smem + 2 * 128 * 64; // [2][128][64] unpadded, swizzled
#define OTS 140
    u16* OT  = smem;                // [128][140] aliased after final sync

    const int blk = blockIdx.x;          // rt*12 + ct
    const int rt = blk / 12;
    const int ct = blk - rt * 12;
    const int b  = rt >> 4;
    const int l0 = (rt & 15) * 128;
    const int tid  = threadIdx.x;
    const int wave = tid >> 6;
    const int lane = tid & 63;
    const int quad = lane >> 4;
    const int l16  = lane & 15;
    const int e7   = l16 & 7;
    const int wx = wave & 1;             // n half
    const int wy = wave >> 1;            // m half

    float4v acc[4][4];
#pragma unroll
    for (int mt = 0; mt < 4; ++mt)
#pragma unroll
        for (int nt = 0; nt < 4; ++nt) acc[mt][nt] = (float4v){0.f, 0.f, 0.f, 0.f};

    const int rowW = wave * 32;
    const int lrow = lane >> 3;          // 0..7
    const int g8   = (((lane & 7) ^ lrow)) * 8;
    auto stage = [&](int kc, int buf) {
        const int slab = kc >> 3;                // conv tap k (0..2)
        const int i0   = (kc & 7) * 64;          // input-channel slice
        const u16* ga = xp + ((size_t)(b * 2050 + l0 + rowW + slab + lrow)) * 512 + i0 + g8;
        const u16* gb = wt + ((size_t)(ct * 128 + rowW + lrow)) * 1536 + kc * 64 + g8;
        u16* la = Asb + (size_t)(buf * 128 + rowW) * 64;
        u16* lb = Bsb + (size_t)(buf * 128 + rowW) * 64;
#pragma unroll
        for (int j = 0; j < 4; ++j) {
            gld_lds16(ga + (size_t)(j * 8) * 512,  la + (j * 8) * 64);
            gld_lds16(gb + (size_t)(j * 8) * 1536, lb + (j * 8) * 64);
        }
    };

    stage(0, 0);

    for (int kc = 0; kc < 24; ++kc) {
        const int cur = kc & 1;
        __syncthreads();   // drains vmcnt -> chunk kc staged; prev reads done

        if (kc < 23) stage(kc + 1, 1 - cur);

#pragma unroll
        for (int half = 0; half < 2; ++half) {
            const int p = ((half * 4 + quad) ^ e7) * 8;   // swizzled chunk
            short8v aF[4], bF[4];
#pragma unroll
            for (int mt = 0; mt < 4; ++mt)
                aF[mt] = *(const short8v*)&Asb[(size_t)(cur * 128 + wy * 64 + mt * 16 + l16) * 64 + p];
#pragma unroll
            for (int nt = 0; nt < 4; ++nt)
                bF[nt] = *(const short8v*)&Bsb[(size_t)(cur * 128 + wx * 64 + nt * 16 + l16) * 64 + p];
#pragma unroll
            for (int mt = 0; mt < 4; ++mt)
#pragma unroll
                for (int nt = 0; nt < 4; ++nt)
                    acc[mt][nt] = __builtin_amdgcn_mfma_f32_16x16x32_bf16(
                        aF[mt], bF[nt], acc[mt][nt], 0, 0, 0);
        }
    }

    // ---- epilogue stage 1: bias+swish(+QSCALE) in regs -> OT [128 l][128 o]
    __syncthreads();   // all LDS tile reads done; safe to alias as OT
    {
        const int tloc = (ct * 2 + wx) % 3;   // t for this wave's col group
#pragma unroll
        for (int nt = 0; nt < 4; ++nt) {
            int oc = wx * 64 + nt * 16 + l16;           // tile-local col
            float bb = b2f(bias[ct * 128 + oc]);
#pragma unroll
            for (int mt = 0; mt < 4; ++mt)
#pragma unroll
                for (int r = 0; r < 4; ++r) {
                    int lr = wy * 64 + mt * 16 + quad * 4 + r;   // tile-local row
                    float y = acc[mt][nt][r] + bb;
                    y = y / (1.f + __expf(-y));                  // swish
                    if (tloc == 0) y *= QSCALE;                  // fold scale*log2e into Q
                    OT[lr * OTS + oc] = f2u(y);
                }
        }
    }
    __syncthreads();

    // ---- epilogue stage 2: coalesced write-out per 64-col group
#pragma unroll
    for (int g = 0; g < 2; ++g) {
        int a  = ct * 2 + g;        // 64-col group index (0..23)
        int t  = a % 3;
        int bh = b * HH + a / 3;
        if (t != 2) {
            u16* base = qkbuf + ((size_t)((bh * 2 + t) * LL + l0)) * HDM;
#pragma unroll
            for (int it = 0; it < 4; ++it) {
                int idx = it * 256 + tid;       // 0..1023
                int l   = idx >> 3;             // 0..127
                int d8  = (idx & 7) * 8;        // 0..56
                uint4 val = *(const uint4*)&OT[l * OTS + g * 64 + d8];
                *(uint4*)(base + (size_t)l * HDM + d8) = val;
            }
        } else {
            u16* base = vbuf + ((size_t)(bh * HDM)) * LL + l0;
#pragma unroll
            for (int it = 0; it < 4; ++it) {
                int idx = it * 256 + tid;       // 0..1023
                int dd  = idx >> 4;             // 0..63
                int l8  = (idx & 15) * 8;       // 0..120
                u16 tmp[8];
#pragma unroll
                for (int j = 0; j < 8; ++j) tmp[j] = OT[(l8 + j) * OTS + g * 64 + dd];
                uint4 val;
                val.x = (unsigned)tmp[0] | ((unsigned)tmp[1] << 16);
                val.y = (unsigned)tmp[2] | ((unsigned)tmp[3] << 16);
                val.z = (unsigned)tmp[4] | ((unsigned)tmp[5] << 16);
                val.w = (unsigned)tmp[6] | ((unsigned)tmp[7] << 16);
                *(uint4*)(base + (size_t)dd * LL + l8) = val;
            }
        }
    }
#undef OTS
}

// -------------------------------------------------------------------------
// Kernel 2: MFMA flash attention per (b,h) — verified R12 form: m-chunk=128,
// static softmax (M=0, exp2 domain, QSCALE pre-folded), 16 barriers, row-sum
// via ones-column MFMA, zero bank conflicts.
// -------------------------------------------------------------------------
__global__ __launch_bounds__(256) void attn_mfma_kernel(
    const u16* __restrict__ qk,    // [B*H][2][L][64]
    const u16* __restrict__ v,     // [B*H][64][L]
    u16* __restrict__ newv)        // [B][L][512]
{
    __shared__ u16 kts[2][128][64];  // [buf][m][d] swizzled
    __shared__ u16 vts[2][64][128];  // [buf][d][m] swizzled
    __shared__ u16 pts[4][16][76];   // per-wave P [w][m], padded stride

    const int blkid = blockIdx.x;        // bh*32 + wchunk
    const int bh = blkid >> 5;
    const int wc = blkid & 31;
    const int b  = bh >> 3;
    const int h  = bh & 7;
    const int tid  = threadIdx.x;
    const int wave = tid >> 6;
    const int lane = tid & 63;
    const int quad = lane >> 4;
    const int l16  = lane & 15;
    const int e7   = l16 & 7;

    const u16* qbase = qk + ((size_t)(bh * 2 + 0)) * LL * HDM;
    const u16* kbase = qk + ((size_t)(bh * 2 + 1)) * LL * HDM;
    const u16* vbase = v + (size_t)bh * HDM * LL;

    const int w0 = wc * 64 + wave * 16;   // this wave's 16 queries

    short8v qfrag[2];
    qfrag[0] = *(const short8v*)(qbase + (size_t)(w0 + l16) * HDM + quad * 8);
    qfrag[1] = *(const short8v*)(qbase + (size_t)(w0 + l16) * HDM + 32 + quad * 8);

    // ones-column B-frag for row-sum MFMA: B[n=l16][k]=1 iff n==0
    short8v vones;
    {
        short o1 = (l16 == 0) ? (short)0x3F80 : (short)0;
#pragma unroll
        for (int j = 0; j < 8; ++j) vones[j] = o1;
    }

    float4v oacc[4];
#pragma unroll
    for (int dt = 0; dt < 4; ++dt) oacc[dt] = (float4v){0.f, 0.f, 0.f, 0.f};
    float4v lacc = (float4v){0.f, 0.f, 0.f, 0.f};

    // staging: wave stages 32 K rows (4 gld x 8 rows) + 16 V rows (4 gld x
    // 4 rows of 128) per 128-m chunk.
    const int rbK   = wave * 32;
    const int lrowK = lane >> 3;          // 0..7
    const int gK    = ((lane & 7) ^ lrowK) * 8;
    const int rbV   = wave * 16;
    const int lrowV = lane >> 4;          // 0..3
    auto stage = [&](int ic, int buf) {
        const int m0 = ic * 128;
#pragma unroll
        for (int j = 0; j < 4; ++j) {
            gld_lds16(kbase + (size_t)(m0 + rbK + j * 8 + lrowK) * HDM + gK,
                      &kts[buf][rbK + j * 8][0]);
            const int vrow = j * 4 + lrowV;           // row&15 (rbV mult of 16)
            gld_lds16(vbase + (size_t)(rbV + vrow) * LL + m0 + (((lane & 15) ^ vrow) * 8),
                      &vts[buf][rbV + j * 4][0]);
        }
    };

    stage(0, 0);

    for (int ic = 0; ic < 16; ++ic) {
        const int cur = ic & 1;
        __syncthreads();   // drains vmcnt -> chunk ic staged; prev reads done

        if (ic < 15) stage(ic + 1, 1 - cur);

        // S = Q.K^T for all 8 m-tiles of this 128-m chunk
        float4v s[8];
#pragma unroll
        for (int mt = 0; mt < 8; ++mt) {
            s[mt] = (float4v){0.f, 0.f, 0.f, 0.f};
            short8v b0 = *(const short8v*)&kts[cur][mt * 16 + l16][((quad) ^ e7) * 8];
            s[mt] = __builtin_amdgcn_mfma_f32_16x16x32_bf16(qfrag[0], b0, s[mt], 0, 0, 0);
            short8v b1 = *(const short8v*)&kts[cur][mt * 16 + l16][((quad + 4) ^ e7) * 8];
            s[mt] = __builtin_amdgcn_mfma_f32_16x16x32_bf16(qfrag[1], b1, s[mt], 0, 0, 0);
        }

        // per 64-m half: P = exp2(S) -> pts -> A-frags -> lacc/oacc MFMA
#pragma unroll
        for (int g = 0; g < 2; ++g) {
#pragma unroll
            for (int mt4 = 0; mt4 < 4; ++mt4)
#pragma unroll
                for (int r = 0; r < 4; ++r)
                    pts[wave][quad * 4 + r][mt4 * 16 + l16] =
                        f2u(__builtin_amdgcn_exp2f(s[g * 4 + mt4][r]));

            short8v pa0 = *(const short8v*)&pts[wave][l16][quad * 8];
            short8v pa1 = *(const short8v*)&pts[wave][l16][32 + quad * 8];

            lacc = __builtin_amdgcn_mfma_f32_16x16x32_bf16(pa0, vones, lacc, 0, 0, 0);
            lacc = __builtin_amdgcn_mfma_f32_16x16x32_bf16(pa1, vones, lacc, 0, 0, 0);

#pragma unroll
            for (int dt = 0; dt < 4; ++dt) {
                short8v v0 = *(const short8v*)&vts[cur][dt * 16 + l16][((g * 8 + quad) ^ l16) * 8];
                oacc[dt] = __builtin_amdgcn_mfma_f32_16x16x32_bf16(pa0, v0, oacc[dt], 0, 0, 0);
                short8v v1 = *(const short8v*)&vts[cur][dt * 16 + l16][((g * 8 + 4 + quad) ^ l16) * 8];
                oacc[dt] = __builtin_amdgcn_mfma_f32_16x16x32_bf16(pa1, v1, oacc[dt], 0, 0, 0);
            }
        }
    }

    // l_run[r] lives in lane (quad, l16==0) of lacc[r]; broadcast per quad
    float inv[4];
#pragma unroll
    for (int r = 0; r < 4; ++r) {
        float lsum = __shfl(lacc[r], quad * 16);
        inv[r] = 1.f / lsum;
    }
    u16* ob = newv + (size_t)b * LL * 512 + h * 64;
#pragma unroll
    for (int dt = 0; dt < 4; ++dt)
#pragma unroll
        for (int r = 0; r < 4; ++r) {
            int w = w0 + quad * 4 + r;
            ob[(size_t)w * 512 + dt * 16 + l16] = f2u(oacc[dt][r] * inv[r]);
        }
}

// -------------------------------------------------------------------------
// Kernel 3: MFMA FC + swish + residual + layernorm, fused. (unchanged R12)
// -------------------------------------------------------------------------
__global__ __launch_bounds__(256) void fc_ln_mfma_kernel(
    const u16* __restrict__ newv,    // [4096][512] bf16
    const u16* __restrict__ fcw,     // [512][512] bf16
    const u16* __restrict__ fcb,     // [512]
    const u16* __restrict__ xp,      // [B][2050][512] padded bf16
    void* __restrict__ out,          // bf16 or f32 per flag
    const int* __restrict__ flagp)
{
    const int l0 = blockIdx.x * 16;
    const int tid  = threadIdx.x;
    const int wave = tid >> 6;
    const int lane = tid & 63;
    const int quad = lane >> 4;
    const int l16  = lane & 15;
    const int col0 = wave * 128;

    const int bb_ = l0 >> 11;   // batch (16-row tiles never straddle)
    const size_t xbase = ((size_t)(bb_ * 2050 + (l0 & 2047) + 1)) * 512;

    __shared__ float psum[4][16], psq[4][16];

    short8v aF[16];
    const u16* arow = newv + (size_t)(l0 + l16) * 512 + quad * 8;
#pragma unroll
    for (int kc = 0; kc < 16; ++kc)
        aF[kc] = *(const short8v*)(arow + kc * 32);

    float4v acc[8];
#pragma unroll
    for (int nt = 0; nt < 8; ++nt) acc[nt] = (float4v){0.f, 0.f, 0.f, 0.f};

#pragma unroll
    for (int nt = 0; nt < 8; ++nt) {
        const u16* brow = fcw + (size_t)(col0 + nt * 16 + l16) * 512 + quad * 8;
#pragma unroll
        for (int kc = 0; kc < 16; ++kc) {
            short8v bF = *(const short8v*)(brow + kc * 32);
            acc[nt] = __builtin_amdgcn_mfma_f32_16x16x32_bf16(aF[kc], bF, acc[nt], 0, 0, 0);
        }
    }

    float z[8][4];
    float rs[4] = {0.f, 0.f, 0.f, 0.f}, rq[4] = {0.f, 0.f, 0.f, 0.f};
#pragma unroll
    for (int nt = 0; nt < 8; ++nt) {
        int col = col0 + nt * 16 + l16;
        float bb = b2f(fcb[col]);
#pragma unroll
        for (int r = 0; r < 4; ++r) {
            int row = quad * 4 + r;
            float y = acc[nt][r] + bb;
            float sw = y / (1.f + __expf(-y));    // swish
            float xv = b2f(xp[xbase + (size_t)row * 512 + col]);
            float zz = xv * 2.f + sw;
            z[nt][r] = zz;
            rs[r] += zz;
            rq[r] += zz * zz;
        }
    }
#pragma unroll
    for (int msk = 1; msk <= 8; msk <<= 1)
#pragma unroll
        for (int r = 0; r < 4; ++r) {
            rs[r] += __shfl_xor(rs[r], msk);
            rq[r] += __shfl_xor(rq[r], msk);
        }
    if (l16 == 0) {
#pragma unroll
        for (int r = 0; r < 4; ++r) {
            psum[wave][quad * 4 + r] = rs[r];
            psq[wave][quad * 4 + r]  = rq[r];
        }
    }
    __syncthreads();

    float mu[4], inv[4];
#pragma unroll
    for (int r = 0; r < 4; ++r) {
        int row = quad * 4 + r;
        float s = psum[0][row] + psum[1][row] + psum[2][row] + psum[3][row];
        float q = psq[0][row] + psq[1][row] + psq[2][row] + psq[3][row];
        float m = s * (1.f / 512.f);
        float var = q * (1.f / 512.f) - m * m;
        mu[r] = m;
        inv[r] = rsqrtf(var + 1e-5f);
    }

    const int flag = *flagp;
#pragma unroll
    for (int nt = 0; nt < 8; ++nt) {
        int col = col0 + nt * 16 + l16;
#pragma unroll
        for (int r = 0; r < 4; ++r) {
            int row = quad * 4 + r;
            float val = (z[nt][r] - mu[r]) * inv[r];
            if (flag) ((float*)out)[(size_t)(l0 + row) * 512 + col] = val;
            else      ((u16*)out)[(size_t)(l0 + row) * 512 + col] = f2u(val);
        }
    }
}

extern "C" void kernel_launch(void* const* d_in, const int* in_sizes, int n_in,
                              void* d_out, int out_size, void* d_ws, size_t ws_size,
                              hipStream_t stream) {
    (void)in_sizes; (void)n_in; (void)out_size; (void)ws_size;

    char* ws = (char*)d_ws;
    int* flag = (int*)ws;
    u16* xp   = (u16*)(ws + 256);        // [2][2050][512] 4,198,400 B -> ends 4,198,656
    u16* wtc  = (u16*)(ws + 4198656);    // [1536][1536] 4,718,592 B  -> ends 8,917,248
    u16* bc   = (u16*)(ws + 8917248);    // 3,072 B  -> ends 8,920,320
    u16* fwc  = (u16*)(ws + 8920320);    // 524,288 B -> ends 9,444,608
    u16* fbc  = (u16*)(ws + 9444608);    // 1,024 B  -> ends 9,445,632
    u16* qkb  = (u16*)(ws + 9445632);    // [16][2][2048][64] = 8 MB -> ends 17,834,240
    u16* vb   = (u16*)(ws + 17834240);   // [16][64][2048]    = 4 MB -> ends 22,028,544
    u16* nvc  = (u16*)(ws + 22028544);   // [2][2048][512]    = 4 MB -> ends 26,222,848

    detect_kernel<<<dim3(1), dim3(64), 0, stream>>>((const u16*)d_in[0], flag);

    // unified prep: 1024 (xpad) + 1152 (convw) + 129 (small) = 2305 blocks
    prep_kernel<<<dim3(2305), dim3(256), 0, stream>>>(
        d_in[0], d_in[1], d_in[2], d_in[3], d_in[4],
        xp, wtc, bc, fwc, fbc, flag);

    conv_mfma_kernel<<<dim3(32 * 12), dim3(256), 0, stream>>>(xp, wtc, bc, qkb, vb);
    attn_mfma_kernel<<<dim3(BB * HH * (LL / 64)), dim3(256), 0, stream>>>(qkb, vb, nvc);
    fc_ln_mfma_kernel<<<dim3(256), dim3(256), 0, stream>>>(nvc, fwc, fbc, xp, d_out, flag);
}

// Round 17
// 169.391 us; speedup vs baseline: 1.0652x; 1.0040x over previous
//
#include <hip/hip_runtime.h>
#include <hip/hip_bf16.h>

// Problem constants
#define BB 2
#define LL 2048
#define DD 512
#define HH 8
#define HDM 64
#define SCALE 0.022097086912079608f    // 1/sqrt(2048)
#define QSCALE 0.03187935766f          // SCALE * log2(e)  (exp2-domain softmax)

typedef __hip_bfloat16 bf16;
typedef unsigned short u16;
typedef __attribute__((ext_vector_type(8))) short short8v;   // 8 bf16 (4 VGPRs)
typedef __attribute__((ext_vector_type(4))) float float4v;   // 4 fp32 acc

// Input element counts
#define XN  2097152    // 2*2048*512
#define WN  2359296    // 1536*512*3
#define BN  1536
#define FWN 262144     // 512*512
#define FBN 512

__device__ __forceinline__ float b2f(u16 u) {
    return __uint_as_float(((unsigned int)u) << 16);
}
__device__ __forceinline__ u16 f2u(float f) {
    bf16 h = __float2bfloat16(f);
    u16 r;
    __builtin_memcpy(&r, &h, 2);
    return r;
}
__device__ __forceinline__ uint4 pack8(const float* f) {
    uint4 p;
    p.x = (unsigned)f2u(f[0]) | ((unsigned)f2u(f[1]) << 16);
    p.y = (unsigned)f2u(f[2]) | ((unsigned)f2u(f[3]) << 16);
    p.z = (unsigned)f2u(f[4]) | ((unsigned)f2u(f[5]) << 16);
    p.w = (unsigned)f2u(f[6]) | ((unsigned)f2u(f[7]) << 16);
    return p;
}

// async 16-B global -> LDS copy (lds dest = wave-uniform base + lane*16)
__device__ __forceinline__ void gld_lds16(const u16* g, u16* l) {
    __builtin_amdgcn_global_load_lds(
        (const __attribute__((address_space(1))) unsigned int*)g,
        (__attribute__((address_space(3))) unsigned int*)l, 16, 0, 0);
}

// dtype detect (f32 vs bf16 inputs), computed locally per wave — all waves
// read the same first 256 half-words of raw x, so result is uniform and
// deterministic across all blocks/kernels. f32 data reinterpreted as bf16
// yields wild exponents/NaN in the low halves -> flag=1.
__device__ __forceinline__ int detect_flag(const u16* __restrict__ xraw) {
    int bad = 0;
    int lane = threadIdx.x & 63;
    for (int i = lane; i < 256; i += 64) {
        float v = b2f(xraw[i]);
        if (!(fabsf(v) < 100.f)) bad = 1;   // catches NaN too
    }
    return (__ballot(bad) != 0ull) ? 1 : 0;
}

__device__ __forceinline__ void conv8(const void* src, u16* dst, size_t i, int flag) {
    if (flag) {
        const float* s = (const float*)src;
        float f[8];
        float4 a = *(const float4*)(s + i);
        float4 b = *(const float4*)(s + i + 4);
        f[0] = a.x; f[1] = a.y; f[2] = a.z; f[3] = a.w;
        f[4] = b.x; f[5] = b.y; f[6] = b.z; f[7] = b.w;
        *(uint4*)(dst + i) = pack8(f);
    } else {
        *(uint4*)(dst + i) = *(const uint4*)((const u16*)src + i);
    }
}

// -------------------------------------------------------------------------
// Kernel 0: unified prep — one launch, block-range branch:
//   [0,1024)    : x -> zero-guard-padded xp[B][2050][512] (+ guard rows)
//   [1024,2176) : cnn_w canonicalize + transpose [o][i][k]->[o][k*512+i]
//   [2176,2305) : cnn_b + fc_w + fc_b converts
// flag computed in-kernel (detect_flag) — no separate detect launch.
// -------------------------------------------------------------------------
__global__ __launch_bounds__(256) void prep_kernel(
    const void* __restrict__ xsrc, const void* __restrict__ wsrc,
    const void* __restrict__ bsrc, const void* __restrict__ fwsrc,
    const void* __restrict__ fbsrc,
    u16* __restrict__ xp, u16* __restrict__ wt,
    u16* __restrict__ bc, u16* __restrict__ fwc, u16* __restrict__ fbc)
{
    const int flag = detect_flag((const u16*)xsrc);
    const int bid = blockIdx.x;

    if (bid < 1024) {
        // ---- xpad ----
        int idx = bid * 256 + threadIdx.x;           // octet id, < 2*2048*64
        if (idx < 256) {
            int b2  = idx >> 7;
            int r2  = (idx >> 6) & 1;
            int c82 = (idx & 63) * 8;
            size_t off = ((size_t)(b2 * 2050 + (r2 ? 2049 : 0))) * 512 + c82;
            uint4 z = {0u, 0u, 0u, 0u};
            *(uint4*)(xp + off) = z;
        }
        int b   = idx / (LL * 64);
        int rem = idx - b * (LL * 64);
        int l   = rem >> 6;
        int c8  = (rem & 63) * 8;
        size_t si = ((size_t)(b * LL + l)) * 512 + c8;
        size_t di = ((size_t)(b * 2050 + l + 1)) * 512 + c8;
        if (flag) {
            const float* s = (const float*)xsrc;
            float f[8];
            float4 a = *(const float4*)(s + si);
            float4 bq = *(const float4*)(s + si + 4);
            f[0] = a.x; f[1] = a.y; f[2] = a.z; f[3] = a.w;
            f[4] = bq.x; f[5] = bq.y; f[6] = bq.z; f[7] = bq.w;
            *(uint4*)(xp + di) = pack8(f);
        } else {
            *(uint4*)(xp + di) = *(const uint4*)((const u16*)xsrc + si);
        }
    } else if (bid < 2176) {
        // ---- convw ----
        int idx = (bid - 1024) * 256 + threadIdx.x;  // < 1536*3*64
        int i8  = idx & 63;
        int rem = idx >> 6;
        int k   = rem % 3;
        int o   = rem / 3;
        float f[8];
        if (flag) {
            const float* s = (const float*)wsrc;
#pragma unroll
            for (int j = 0; j < 8; ++j) f[j] = s[(size_t)o * 1536 + (i8 * 8 + j) * 3 + k];
        } else {
            const u16* s = (const u16*)wsrc;
#pragma unroll
            for (int j = 0; j < 8; ++j) f[j] = b2f(s[(size_t)o * 1536 + (i8 * 8 + j) * 3 + k]);
        }
        *(uint4*)(wt + (size_t)o * 1536 + k * 512 + i8 * 8) = pack8(f);
    } else {
        // ---- small converts ----
        int o = (bid - 2176) * 256 + threadIdx.x;    // octet id
        if (o < BN / 8) {
            conv8(bsrc, bc, (size_t)o * 8, flag);
        } else if (o < BN / 8 + FWN / 8) {
            conv8(fwsrc, fwc, (size_t)(o - BN / 8) * 8, flag);
        } else if (o < BN / 8 + FWN / 8 + FBN / 8) {
            conv8(fbsrc, fbc, (size_t)(o - BN / 8 - FWN / 8) * 8, flag);
        }
    }
}

// -------------------------------------------------------------------------
// Kernel 1: conv GEMM — R12-verified form: 128x128 tiles, 384 blocks,
// m97-style K-loop (global_load_lds 16B, XOR bank swizzle, 1 barrier/chunk),
// LDS-transpose epilogue (coalesced qkbuf/vbuf writes), QSCALE fold into Q.
// -------------------------------------------------------------------------
__global__ __launch_bounds__(256) void conv_mfma_kernel(
    const u16* __restrict__ xp,     // [B][2050][512] padded bf16
    const u16* __restrict__ wt,     // [1536][1536] = [o][k*512+i]
    const u16* __restrict__ bias,   // [1536]
    u16* __restrict__ qkbuf,        // [B*H][2][L][64]
    u16* __restrict__ vbuf)         // [B*H][64][L]
{
    __shared__ u16 smem[32768];     // 65536 B
    u16* Asb = smem;                // [2][128][64] unpadded, swizzled
    u16* Bsb = smem + 2 * 128 * 64; // [2][128][64] unpadded, swizzled
#define OTS 140
    u16* OT  = smem;                // [128][140] aliased after final sync

    const int blk = blockIdx.x;          // rt*12 + ct
    const int rt = blk / 12;
    const int ct = blk - rt * 12;
    const int b  = rt >> 4;
    const int l0 = (rt & 15) * 128;
    const int tid  = threadIdx.x;
    const int wave = tid >> 6;
    const int lane = tid & 63;
    const int quad = lane >> 4;
    const int l16  = lane & 15;
    const int e7   = l16 & 7;
    const int wx = wave & 1;             // n half
    const int wy = wave >> 1;            // m half

    float4v acc[4][4];
#pragma unroll
    for (int mt = 0; mt < 4; ++mt)
#pragma unroll
        for (int nt = 0; nt < 4; ++nt) acc[mt][nt] = (float4v){0.f, 0.f, 0.f, 0.f};

    const int rowW = wave * 32;
    const int lrow = lane >> 3;          // 0..7
    const int g8   = (((lane & 7) ^ lrow)) * 8;
    auto stage = [&](int kc, int buf) {
        const int slab = kc >> 3;                // conv tap k (0..2)
        const int i0   = (kc & 7) * 64;          // input-channel slice
        const u16* ga = xp + ((size_t)(b * 2050 + l0 + rowW + slab + lrow)) * 512 + i0 + g8;
        const u16* gb = wt + ((size_t)(ct * 128 + rowW + lrow)) * 1536 + kc * 64 + g8;
        u16* la = Asb + (size_t)(buf * 128 + rowW) * 64;
        u16* lb = Bsb + (size_t)(buf * 128 + rowW) * 64;
#pragma unroll
        for (int j = 0; j < 4; ++j) {
            gld_lds16(ga + (size_t)(j * 8) * 512,  la + (j * 8) * 64);
            gld_lds16(gb + (size_t)(j * 8) * 1536, lb + (j * 8) * 64);
        }
    };

    stage(0, 0);

    for (int kc = 0; kc < 24; ++kc) {
        const int cur = kc & 1;
        __syncthreads();   // drains vmcnt -> chunk kc staged; prev reads done

        if (kc < 23) stage(kc + 1, 1 - cur);

#pragma unroll
        for (int half = 0; half < 2; ++half) {
            const int p = ((half * 4 + quad) ^ e7) * 8;   // swizzled chunk
            short8v aF[4], bF[4];
#pragma unroll
            for (int mt = 0; mt < 4; ++mt)
                aF[mt] = *(const short8v*)&Asb[(size_t)(cur * 128 + wy * 64 + mt * 16 + l16) * 64 + p];
#pragma unroll
            for (int nt = 0; nt < 4; ++nt)
                bF[nt] = *(const short8v*)&Bsb[(size_t)(cur * 128 + wx * 64 + nt * 16 + l16) * 64 + p];
#pragma unroll
            for (int mt = 0; mt < 4; ++mt)
#pragma unroll
                for (int nt = 0; nt < 4; ++nt)
                    acc[mt][nt] = __builtin_amdgcn_mfma_f32_16x16x32_bf16(
                        aF[mt], bF[nt], acc[mt][nt], 0, 0, 0);
        }
    }

    // ---- epilogue stage 1: bias+swish(+QSCALE) in regs -> OT [128 l][128 o]
    __syncthreads();   // all LDS tile reads done; safe to alias as OT
    {
        const int tloc = (ct * 2 + wx) % 3;   // t for this wave's col group
#pragma unroll
        for (int nt = 0; nt < 4; ++nt) {
            int oc = wx * 64 + nt * 16 + l16;           // tile-local col
            float bb = b2f(bias[ct * 128 + oc]);
#pragma unroll
            for (int mt = 0; mt < 4; ++mt)
#pragma unroll
                for (int r = 0; r < 4; ++r) {
                    int lr = wy * 64 + mt * 16 + quad * 4 + r;   // tile-local row
                    float y = acc[mt][nt][r] + bb;
                    y = y / (1.f + __expf(-y));                  // swish
                    if (tloc == 0) y *= QSCALE;                  // fold scale*log2e into Q
                    OT[lr * OTS + oc] = f2u(y);
                }
        }
    }
    __syncthreads();

    // ---- epilogue stage 2: coalesced write-out per 64-col group
#pragma unroll
    for (int g = 0; g < 2; ++g) {
        int a  = ct * 2 + g;        // 64-col group index (0..23)
        int t  = a % 3;
        int bh = b * HH + a / 3;
        if (t != 2) {
            u16* base = qkbuf + ((size_t)((bh * 2 + t) * LL + l0)) * HDM;
#pragma unroll
            for (int it = 0; it < 4; ++it) {
                int idx = it * 256 + tid;       // 0..1023
                int l   = idx >> 3;             // 0..127
                int d8  = (idx & 7) * 8;        // 0..56
                uint4 val = *(const uint4*)&OT[l * OTS + g * 64 + d8];
                *(uint4*)(base + (size_t)l * HDM + d8) = val;
            }
        } else {
            u16* base = vbuf + ((size_t)(bh * HDM)) * LL + l0;
#pragma unroll
            for (int it = 0; it < 4; ++it) {
                int idx = it * 256 + tid;       // 0..1023
                int dd  = idx >> 4;             // 0..63
                int l8  = (idx & 15) * 8;       // 0..120
                u16 tmp[8];
#pragma unroll
                for (int j = 0; j < 8; ++j) tmp[j] = OT[(l8 + j) * OTS + g * 64 + dd];
                uint4 val;
                val.x = (unsigned)tmp[0] | ((unsigned)tmp[1] << 16);
                val.y = (unsigned)tmp[2] | ((unsigned)tmp[3] << 16);
                val.z = (unsigned)tmp[4] | ((unsigned)tmp[5] << 16);
                val.w = (unsigned)tmp[6] | ((unsigned)tmp[7] << 16);
                *(uint4*)(base + (size_t)dd * LL + l8) = val;
            }
        }
    }
#undef OTS
}

// -------------------------------------------------------------------------
// Kernel 2: MFMA flash attention per (b,h) — verified R12 form: m-chunk=128,
// static softmax (M=0, exp2 domain, QSCALE pre-folded), 16 barriers, row-sum
// via ones-column MFMA, zero bank conflicts.
// -------------------------------------------------------------------------
__global__ __launch_bounds__(256) void attn_mfma_kernel(
    const u16* __restrict__ qk,    // [B*H][2][L][64]
    const u16* __restrict__ v,     // [B*H][64][L]
    u16* __restrict__ newv)        // [B][L][512]
{
    __shared__ u16 kts[2][128][64];  // [buf][m][d] swizzled
    __shared__ u16 vts[2][64][128];  // [buf][d][m] swizzled
    __shared__ u16 pts[4][16][76];   // per-wave P [w][m], padded stride

    const int blkid = blockIdx.x;        // bh*32 + wchunk
    const int bh = blkid >> 5;
    const int wc = blkid & 31;
    const int b  = bh >> 3;
    const int h  = bh & 7;
    const int tid  = threadIdx.x;
    const int wave = tid >> 6;
    const int lane = tid & 63;
    const int quad = lane >> 4;
    const int l16  = lane & 15;
    const int e7   = l16 & 7;

    const u16* qbase = qk + ((size_t)(bh * 2 + 0)) * LL * HDM;
    const u16* kbase = qk + ((size_t)(bh * 2 + 1)) * LL * HDM;
    const u16* vbase = v + (size_t)bh * HDM * LL;

    const int w0 = wc * 64 + wave * 16;   // this wave's 16 queries

    short8v qfrag[2];
    qfrag[0] = *(const short8v*)(qbase + (size_t)(w0 + l16) * HDM + quad * 8);
    qfrag[1] = *(const short8v*)(qbase + (size_t)(w0 + l16) * HDM + 32 + quad * 8);

    // ones-column B-frag for row-sum MFMA: B[n=l16][k]=1 iff n==0
    short8v vones;
    {
        short o1 = (l16 == 0) ? (short)0x3F80 : (short)0;
#pragma unroll
        for (int j = 0; j < 8; ++j) vones[j] = o1;
    }

    float4v oacc[4];
#pragma unroll
    for (int dt = 0; dt < 4; ++dt) oacc[dt] = (float4v){0.f, 0.f, 0.f, 0.f};
    float4v lacc = (float4v){0.f, 0.f, 0.f, 0.f};

    // staging: wave stages 32 K rows (4 gld x 8 rows) + 16 V rows (4 gld x
    // 4 rows of 128) per 128-m chunk.
    const int rbK   = wave * 32;
    const int lrowK = lane >> 3;          // 0..7
    const int gK    = ((lane & 7) ^ lrowK) * 8;
    const int rbV   = wave * 16;
    const int lrowV = lane >> 4;          // 0..3
    auto stage = [&](int ic, int buf) {
        const int m0 = ic * 128;
#pragma unroll
        for (int j = 0; j < 4; ++j) {
            gld_lds16(kbase + (size_t)(m0 + rbK + j * 8 + lrowK) * HDM + gK,
                      &kts[buf][rbK + j * 8][0]);
            const int vrow = j * 4 + lrowV;           // row&15 (rbV mult of 16)
            gld_lds16(vbase + (size_t)(rbV + vrow) * LL + m0 + (((lane & 15) ^ vrow) * 8),
                      &vts[buf][rbV + j * 4][0]);
        }
    };

    stage(0, 0);

    for (int ic = 0; ic < 16; ++ic) {
        const int cur = ic & 1;
        __syncthreads();   // drains vmcnt -> chunk ic staged; prev reads done

        if (ic < 15) stage(ic + 1, 1 - cur);

        // S = Q.K^T for all 8 m-tiles of this 128-m chunk
        float4v s[8];
#pragma unroll
        for (int mt = 0; mt < 8; ++mt) {
            s[mt] = (float4v){0.f, 0.f, 0.f, 0.f};
            short8v b0 = *(const short8v*)&kts[cur][mt * 16 + l16][((quad) ^ e7) * 8];
            s[mt] = __builtin_amdgcn_mfma_f32_16x16x32_bf16(qfrag[0], b0, s[mt], 0, 0, 0);
            short8v b1 = *(const short8v*)&kts[cur][mt * 16 + l16][((quad + 4) ^ e7) * 8];
            s[mt] = __builtin_amdgcn_mfma_f32_16x16x32_bf16(qfrag[1], b1, s[mt], 0, 0, 0);
        }

        // per 64-m half: P = exp2(S) -> pts -> A-frags -> lacc/oacc MFMA
#pragma unroll
        for (int g = 0; g < 2; ++g) {
#pragma unroll
            for (int mt4 = 0; mt4 < 4; ++mt4)
#pragma unroll
                for (int r = 0; r < 4; ++r)
                    pts[wave][quad * 4 + r][mt4 * 16 + l16] =
                        f2u(__builtin_amdgcn_exp2f(s[g * 4 + mt4][r]));

            short8v pa0 = *(const short8v*)&pts[wave][l16][quad * 8];
            short8v pa1 = *(const short8v*)&pts[wave][l16][32 + quad * 8];

            lacc = __builtin_amdgcn_mfma_f32_16x16x32_bf16(pa0, vones, lacc, 0, 0, 0);
            lacc = __builtin_amdgcn_mfma_f32_16x16x32_bf16(pa1, vones, lacc, 0, 0, 0);

#pragma unroll
            for (int dt = 0; dt < 4; ++dt) {
                short8v v0 = *(const short8v*)&vts[cur][dt * 16 + l16][((g * 8 + quad) ^ l16) * 8];
                oacc[dt] = __builtin_amdgcn_mfma_f32_16x16x32_bf16(pa0, v0, oacc[dt], 0, 0, 0);
                short8v v1 = *(const short8v*)&vts[cur][dt * 16 + l16][((g * 8 + 4 + quad) ^ l16) * 8];
                oacc[dt] = __builtin_amdgcn_mfma_f32_16x16x32_bf16(pa1, v1, oacc[dt], 0, 0, 0);
            }
        }
    }

    // l_run[r] lives in lane (quad, l16==0) of lacc[r]; broadcast per quad
    float inv[4];
#pragma unroll
    for (int r = 0; r < 4; ++r) {
        float lsum = __shfl(lacc[r], quad * 16);
        inv[r] = 1.f / lsum;
    }
    u16* ob = newv + (size_t)b * LL * 512 + h * 64;
#pragma unroll
    for (int dt = 0; dt < 4; ++dt)
#pragma unroll
        for (int r = 0; r < 4; ++r) {
            int w = w0 + quad * 4 + r;
            ob[(size_t)w * 512 + dt * 16 + l16] = f2u(oacc[dt][r] * inv[r]);
        }
}

// -------------------------------------------------------------------------
// Kernel 3: MFMA FC + swish + residual + layernorm, fused. Output dtype
// per in-kernel detect_flag on raw x (no flag dependency).
// -------------------------------------------------------------------------
__global__ __launch_bounds__(256) void fc_ln_mfma_kernel(
    const u16* __restrict__ newv,    // [4096][512] bf16
    const u16* __restrict__ fcw,     // [512][512] bf16
    const u16* __restrict__ fcb,     // [512]
    const u16* __restrict__ xp,      // [B][2050][512] padded bf16
    const u16* __restrict__ xraw,    // raw x input (dtype detect)
    void* __restrict__ out)          // bf16 or f32 per flag
{
    const int flag = detect_flag(xraw);
    const int l0 = blockIdx.x * 16;
    const int tid  = threadIdx.x;
    const int wave = tid >> 6;
    const int lane = tid & 63;
    const int quad = lane >> 4;
    const int l16  = lane & 15;
    const int col0 = wave * 128;

    const int bb_ = l0 >> 11;   // batch (16-row tiles never straddle)
    const size_t xbase = ((size_t)(bb_ * 2050 + (l0 & 2047) + 1)) * 512;

    __shared__ float psum[4][16], psq[4][16];

    short8v aF[16];
    const u16* arow = newv + (size_t)(l0 + l16) * 512 + quad * 8;
#pragma unroll
    for (int kc = 0; kc < 16; ++kc)
        aF[kc] = *(const short8v*)(arow + kc * 32);

    float4v acc[8];
#pragma unroll
    for (int nt = 0; nt < 8; ++nt) acc[nt] = (float4v){0.f, 0.f, 0.f, 0.f};

#pragma unroll
    for (int nt = 0; nt < 8; ++nt) {
        const u16* brow = fcw + (size_t)(col0 + nt * 16 + l16) * 512 + quad * 8;
#pragma unroll
        for (int kc = 0; kc < 16; ++kc) {
            short8v bF = *(const short8v*)(brow + kc * 32);
            acc[nt] = __builtin_amdgcn_mfma_f32_16x16x32_bf16(aF[kc], bF, acc[nt], 0, 0, 0);
        }
    }

    float z[8][4];
    float rs[4] = {0.f, 0.f, 0.f, 0.f}, rq[4] = {0.f, 0.f, 0.f, 0.f};
#pragma unroll
    for (int nt = 0; nt < 8; ++nt) {
        int col = col0 + nt * 16 + l16;
        float bb = b2f(fcb[col]);
#pragma unroll
        for (int r = 0; r < 4; ++r) {
            int row = quad * 4 + r;
            float y = acc[nt][r] + bb;
            float sw = y / (1.f + __expf(-y));    // swish
            float xv = b2f(xp[xbase + (size_t)row * 512 + col]);
            float zz = xv * 2.f + sw;
            z[nt][r] = zz;
            rs[r] += zz;
            rq[r] += zz * zz;
        }
    }
#pragma unroll
    for (int msk = 1; msk <= 8; msk <<= 1)
#pragma unroll
        for (int r = 0; r < 4; ++r) {
            rs[r] += __shfl_xor(rs[r], msk);
            rq[r] += __shfl_xor(rq[r], msk);
        }
    if (l16 == 0) {
#pragma unroll
        for (int r = 0; r < 4; ++r) {
            psum[wave][quad * 4 + r] = rs[r];
            psq[wave][quad * 4 + r]  = rq[r];
        }
    }
    __syncthreads();

    float mu[4], inv[4];
#pragma unroll
    for (int r = 0; r < 4; ++r) {
        int row = quad * 4 + r;
        float s = psum[0][row] + psum[1][row] + psum[2][row] + psum[3][row];
        float q = psq[0][row] + psq[1][row] + psq[2][row] + psq[3][row];
        float m = s * (1.f / 512.f);
        float var = q * (1.f / 512.f) - m * m;
        mu[r] = m;
        inv[r] = rsqrtf(var + 1e-5f);
    }

#pragma unroll
    for (int nt = 0; nt < 8; ++nt) {
        int col = col0 + nt * 16 + l16;
#pragma unroll
        for (int r = 0; r < 4; ++r) {
            int row = quad * 4 + r;
            float val = (z[nt][r] - mu[r]) * inv[r];
            if (flag) ((float*)out)[(size_t)(l0 + row) * 512 + col] = val;
            else      ((u16*)out)[(size_t)(l0 + row) * 512 + col] = f2u(val);
        }
    }
}

extern "C" void kernel_launch(void* const* d_in, const int* in_sizes, int n_in,
                              void* d_out, int out_size, void* d_ws, size_t ws_size,
                              hipStream_t stream) {
    (void)in_sizes; (void)n_in; (void)out_size; (void)ws_size;

    char* ws = (char*)d_ws;
    u16* xp   = (u16*)(ws + 256);        // [2][2050][512] 4,198,400 B -> ends 4,198,656
    u16* wtc  = (u16*)(ws + 4198656);    // [1536][1536] 4,718,592 B  -> ends 8,917,248
    u16* bc   = (u16*)(ws + 8917248);    // 3,072 B  -> ends 8,920,320
    u16* fwc  = (u16*)(ws + 8920320);    // 524,288 B -> ends 9,444,608
    u16* fbc  = (u16*)(ws + 9444608);    // 1,024 B  -> ends 9,445,632
    u16* qkb  = (u16*)(ws + 9445632);    // [16][2][2048][64] = 8 MB -> ends 17,834,240
    u16* vb   = (u16*)(ws + 17834240);   // [16][64][2048]    = 4 MB -> ends 22,028,544
    u16* nvc  = (u16*)(ws + 22028544);   // [2][2048][512]    = 4 MB -> ends 26,222,848

    // unified prep: 1024 (xpad) + 1152 (convw) + 129 (small) = 2305 blocks
    prep_kernel<<<dim3(2305), dim3(256), 0, stream>>>(
        d_in[0], d_in[1], d_in[2], d_in[3], d_in[4],
        xp, wtc, bc, fwc, fbc);

    conv_mfma_kernel<<<dim3(32 * 12), dim3(256), 0, stream>>>(xp, wtc, bc, qkb, vb);
    attn_mfma_kernel<<<dim3(BB * HH * (LL / 64)), dim3(256), 0, stream>>>(qkb, vb, nvc);
    fc_ln_mfma_kernel<<<dim3(256), dim3(256), 0, stream>>>(
        nvc, fwc, fbc, xp, (const u16*)d_in[0], d_out);
}

// Round 19
// 168.757 us; speedup vs baseline: 1.0692x; 1.0038x over previous
//
#include <hip/hip_runtime.h>
#include <hip/hip_bf16.h>

// Problem constants
#define BB 2
#define LL 2048
#define DD 512
#define HH 8
#define HDM 64
#define SCALE 0.022097086912079608f    // 1/sqrt(2048)
#define QSCALE 0.03187935766f          // SCALE * log2(e)  (exp2-domain softmax)

typedef __hip_bfloat16 bf16;
typedef unsigned short u16;
typedef __attribute__((ext_vector_type(8))) short short8v;   // 8 bf16 (4 VGPRs)
typedef __attribute__((ext_vector_type(4))) float float4v;   // 4 fp32 acc

// Input element counts
#define XN  2097152    // 2*2048*512
#define WN  2359296    // 1536*512*3
#define BN  1536
#define FWN 262144     // 512*512
#define FBN 512

__device__ __forceinline__ float b2f(u16 u) {
    return __uint_as_float(((unsigned int)u) << 16);
}
__device__ __forceinline__ u16 f2u(float f) {
    bf16 h = __float2bfloat16(f);
    u16 r;
    __builtin_memcpy(&r, &h, 2);
    return r;
}
__device__ __forceinline__ uint4 pack8(const float* f) {
    uint4 p;
    p.x = (unsigned)f2u(f[0]) | ((unsigned)f2u(f[1]) << 16);
    p.y = (unsigned)f2u(f[2]) | ((unsigned)f2u(f[3]) << 16);
    p.z = (unsigned)f2u(f[4]) | ((unsigned)f2u(f[5]) << 16);
    p.w = (unsigned)f2u(f[6]) | ((unsigned)f2u(f[7]) << 16);
    return p;
}

// async 16-B global -> LDS copy (lds dest = wave-uniform base + lane*16)
__device__ __forceinline__ void gld_lds16(const u16* g, u16* l) {
    __builtin_amdgcn_global_load_lds(
        (const __attribute__((address_space(1))) unsigned int*)g,
        (__attribute__((address_space(3))) unsigned int*)l, 16, 0, 0);
}

// dtype detect (f32 vs bf16 inputs), computed locally per wave — all waves
// read the same first 256 half-words of raw x, so result is uniform and
// deterministic across all blocks/kernels.
__device__ __forceinline__ int detect_flag(const u16* __restrict__ xraw) {
    int bad = 0;
    int lane = threadIdx.x & 63;
    for (int i = lane; i < 256; i += 64) {
        float v = b2f(xraw[i]);
        if (!(fabsf(v) < 100.f)) bad = 1;   // catches NaN too
    }
    return (__ballot(bad) != 0ull) ? 1 : 0;
}

__device__ __forceinline__ void conv8(const void* src, u16* dst, size_t i, int flag) {
    if (flag) {
        const float* s = (const float*)src;
        float f[8];
        float4 a = *(const float4*)(s + i);
        float4 b = *(const float4*)(s + i + 4);
        f[0] = a.x; f[1] = a.y; f[2] = a.z; f[3] = a.w;
        f[4] = b.x; f[5] = b.y; f[6] = b.z; f[7] = b.w;
        *(uint4*)(dst + i) = pack8(f);
    } else {
        *(uint4*)(dst + i) = *(const uint4*)((const u16*)src + i);
    }
}

// -------------------------------------------------------------------------
// Kernel 0: unified prep — one launch, block-range branch:
//   [0,1024)    : x -> zero-guard-padded xp[B][2050][512] (+ guard rows)
//   [1024,2176) : cnn_w canonicalize + transpose [o][i][k]->[o][k*512+i]
//   [2176,2305) : cnn_b + fc_w + fc_b converts
// -------------------------------------------------------------------------
__global__ __launch_bounds__(256) void prep_kernel(
    const void* __restrict__ xsrc, const void* __restrict__ wsrc,
    const void* __restrict__ bsrc, const void* __restrict__ fwsrc,
    const void* __restrict__ fbsrc,
    u16* __restrict__ xp, u16* __restrict__ wt,
    u16* __restrict__ bc, u16* __restrict__ fwc, u16* __restrict__ fbc)
{
    const int flag = detect_flag((const u16*)xsrc);
    const int bid = blockIdx.x;

    if (bid < 1024) {
        // ---- xpad ----
        int idx = bid * 256 + threadIdx.x;           // octet id, < 2*2048*64
        if (idx < 256) {
            int b2  = idx >> 7;
            int r2  = (idx >> 6) & 1;
            int c82 = (idx & 63) * 8;
            size_t off = ((size_t)(b2 * 2050 + (r2 ? 2049 : 0))) * 512 + c82;
            uint4 z = {0u, 0u, 0u, 0u};
            *(uint4*)(xp + off) = z;
        }
        int b   = idx / (LL * 64);
        int rem = idx - b * (LL * 64);
        int l   = rem >> 6;
        int c8  = (rem & 63) * 8;
        size_t si = ((size_t)(b * LL + l)) * 512 + c8;
        size_t di = ((size_t)(b * 2050 + l + 1)) * 512 + c8;
        if (flag) {
            const float* s = (const float*)xsrc;
            float f[8];
            float4 a = *(const float4*)(s + si);
            float4 bq = *(const float4*)(s + si + 4);
            f[0] = a.x; f[1] = a.y; f[2] = a.z; f[3] = a.w;
            f[4] = bq.x; f[5] = bq.y; f[6] = bq.z; f[7] = bq.w;
            *(uint4*)(xp + di) = pack8(f);
        } else {
            *(uint4*)(xp + di) = *(const uint4*)((const u16*)xsrc + si);
        }
    } else if (bid < 2176) {
        // ---- convw ----
        int idx = (bid - 1024) * 256 + threadIdx.x;  // < 1536*3*64
        int i8  = idx & 63;
        int rem = idx >> 6;
        int k   = rem % 3;
        int o   = rem / 3;
        float f[8];
        if (flag) {
            const float* s = (const float*)wsrc;
#pragma unroll
            for (int j = 0; j < 8; ++j) f[j] = s[(size_t)o * 1536 + (i8 * 8 + j) * 3 + k];
        } else {
            const u16* s = (const u16*)wsrc;
#pragma unroll
            for (int j = 0; j < 8; ++j) f[j] = b2f(s[(size_t)o * 1536 + (i8 * 8 + j) * 3 + k]);
        }
        *(uint4*)(wt + (size_t)o * 1536 + k * 512 + i8 * 8) = pack8(f);
    } else {
        // ---- small converts ----
        int o = (bid - 2176) * 256 + threadIdx.x;    // octet id
        if (o < BN / 8) {
            conv8(bsrc, bc, (size_t)o * 8, flag);
        } else if (o < BN / 8 + FWN / 8) {
            conv8(fwsrc, fwc, (size_t)(o - BN / 8) * 8, flag);
        } else if (o < BN / 8 + FWN / 8 + FBN / 8) {
            conv8(fbsrc, fbc, (size_t)(o - BN / 8 - FWN / 8) * 8, flag);
        }
    }
}

// -------------------------------------------------------------------------
// Kernel 1: conv GEMM — R12-verified form: 128x128 tiles, 384 blocks,
// m97-style K-loop (global_load_lds 16B, XOR bank swizzle, 1 barrier/chunk),
// LDS-transpose epilogue (coalesced qkbuf/vbuf writes), QSCALE fold into Q.
// -------------------------------------------------------------------------
__global__ __launch_bounds__(256) void conv_mfma_kernel(
    const u16* __restrict__ xp,     // [B][2050][512] padded bf16
    const u16* __restrict__ wt,     // [1536][1536] = [o][k*512+i]
    const u16* __restrict__ bias,   // [1536]
    u16* __restrict__ qkbuf,        // [B*H][2][L][64]
    u16* __restrict__ vbuf)         // [B*H][64][L]
{
    __shared__ u16 smem[32768];     // 65536 B
    u16* Asb = smem;                // [2][128][64] unpadded, swizzled
    u16* Bsb = smem + 2 * 128 * 64; // [2][128][64] unpadded, swizzled
#define OTS 140
    u16* OT  = smem;                // [128][140] aliased after final sync

    const int blk = blockIdx.x;          // rt*12 + ct
    const int rt = blk / 12;
    const int ct = blk - rt * 12;
    const int b  = rt >> 4;
    const int l0 = (rt & 15) * 128;
    const int tid  = threadIdx.x;
    const int wave = tid >> 6;
    const int lane = tid & 63;
    const int quad = lane >> 4;
    const int l16  = lane & 15;
    const int e7   = l16 & 7;
    const int wx = wave & 1;             // n half
    const int wy = wave >> 1;            // m half

    float4v acc[4][4];
#pragma unroll
    for (int mt = 0; mt < 4; ++mt)
#pragma unroll
        for (int nt = 0; nt < 4; ++nt) acc[mt][nt] = (float4v){0.f, 0.f, 0.f, 0.f};

    const int rowW = wave * 32;
    const int lrow = lane >> 3;          // 0..7
    const int g8   = (((lane & 7) ^ lrow)) * 8;
    auto stage = [&](int kc, int buf) {
        const int slab = kc >> 3;                // conv tap k (0..2)
        const int i0   = (kc & 7) * 64;          // input-channel slice
        const u16* ga = xp + ((size_t)(b * 2050 + l0 + rowW + slab + lrow)) * 512 + i0 + g8;
        const u16* gb = wt + ((size_t)(ct * 128 + rowW + lrow)) * 1536 + kc * 64 + g8;
        u16* la = Asb + (size_t)(buf * 128 + rowW) * 64;
        u16* lb = Bsb + (size_t)(buf * 128 + rowW) * 64;
#pragma unroll
        for (int j = 0; j < 4; ++j) {
            gld_lds16(ga + (size_t)(j * 8) * 512,  la + (j * 8) * 64);
            gld_lds16(gb + (size_t)(j * 8) * 1536, lb + (j * 8) * 64);
        }
    };

    stage(0, 0);

    for (int kc = 0; kc < 24; ++kc) {
        const int cur = kc & 1;
        __syncthreads();   // drains vmcnt -> chunk kc staged; prev reads done

        if (kc < 23) stage(kc + 1, 1 - cur);

#pragma unroll
        for (int half = 0; half < 2; ++half) {
            const int p = ((half * 4 + quad) ^ e7) * 8;   // swizzled chunk
            short8v aF[4], bF[4];
#pragma unroll
            for (int mt = 0; mt < 4; ++mt)
                aF[mt] = *(const short8v*)&Asb[(size_t)(cur * 128 + wy * 64 + mt * 16 + l16) * 64 + p];
#pragma unroll
            for (int nt = 0; nt < 4; ++nt)
                bF[nt] = *(const short8v*)&Bsb[(size_t)(cur * 128 + wx * 64 + nt * 16 + l16) * 64 + p];
#pragma unroll
            for (int mt = 0; mt < 4; ++mt)
#pragma unroll
                for (int nt = 0; nt < 4; ++nt)
                    acc[mt][nt] = __builtin_amdgcn_mfma_f32_16x16x32_bf16(
                        aF[mt], bF[nt], acc[mt][nt], 0, 0, 0);
        }
    }

    // ---- epilogue stage 1: bias+swish(+QSCALE) in regs -> OT [128 l][128 o]
    __syncthreads();   // all LDS tile reads done; safe to alias as OT
    {
        const int tloc = (ct * 2 + wx) % 3;   // t for this wave's col group
#pragma unroll
        for (int nt = 0; nt < 4; ++nt) {
            int oc = wx * 64 + nt * 16 + l16;           // tile-local col
            float bb = b2f(bias[ct * 128 + oc]);
#pragma unroll
            for (int mt = 0; mt < 4; ++mt)
#pragma unroll
                for (int r = 0; r < 4; ++r) {
                    int lr = wy * 64 + mt * 16 + quad * 4 + r;   // tile-local row
                    float y = acc[mt][nt][r] + bb;
                    y = y / (1.f + __expf(-y));                  // swish
                    if (tloc == 0) y *= QSCALE;                  // fold scale*log2e into Q
                    OT[lr * OTS + oc] = f2u(y);
                }
        }
    }
    __syncthreads();

    // ---- epilogue stage 2: coalesced write-out per 64-col group
#pragma unroll
    for (int g = 0; g < 2; ++g) {
        int a  = ct * 2 + g;        // 64-col group index (0..23)
        int t  = a % 3;
        int bh = b * HH + a / 3;
        if (t != 2) {
            u16* base = qkbuf + ((size_t)((bh * 2 + t) * LL + l0)) * HDM;
#pragma unroll
            for (int it = 0; it < 4; ++it) {
                int idx = it * 256 + tid;       // 0..1023
                int l   = idx >> 3;             // 0..127
                int d8  = (idx & 7) * 8;        // 0..56
                uint4 val = *(const uint4*)&OT[l * OTS + g * 64 + d8];
                *(uint4*)(base + (size_t)l * HDM + d8) = val;
            }
        } else {
            u16* base = vbuf + ((size_t)(bh * HDM)) * LL + l0;
#pragma unroll
            for (int it = 0; it < 4; ++it) {
                int idx = it * 256 + tid;       // 0..1023
                int dd  = idx >> 4;             // 0..63
                int l8  = (idx & 15) * 8;       // 0..120
                u16 tmp[8];
#pragma unroll
                for (int j = 0; j < 8; ++j) tmp[j] = OT[(l8 + j) * OTS + g * 64 + dd];
                uint4 val;
                val.x = (unsigned)tmp[0] | ((unsigned)tmp[1] << 16);
                val.y = (unsigned)tmp[2] | ((unsigned)tmp[3] << 16);
                val.z = (unsigned)tmp[4] | ((unsigned)tmp[5] << 16);
                val.w = (unsigned)tmp[6] | ((unsigned)tmp[7] << 16);
                *(uint4*)(base + (size_t)dd * LL + l8) = val;
            }
        }
    }
#undef OTS
}

// -------------------------------------------------------------------------
// Kernel 2: MFMA flash attention per (b,h) — verified R12 form: m-chunk=128,
// static softmax (M=0, exp2 domain, QSCALE pre-folded), 16 barriers, row-sum
// via ones-column MFMA, zero bank conflicts.
// -------------------------------------------------------------------------
__global__ __launch_bounds__(256) void attn_mfma_kernel(
    const u16* __restrict__ qk,    // [B*H][2][L][64]
    const u16* __restrict__ v,     // [B*H][64][L]
    u16* __restrict__ newv)        // [B][L][512]
{
    __shared__ u16 kts[2][128][64];  // [buf][m][d] swizzled
    __shared__ u16 vts[2][64][128];  // [buf][d][m] swizzled
    __shared__ u16 pts[4][16][76];   // per-wave P [w][m], padded stride

    const int blkid = blockIdx.x;        // bh*32 + wchunk
    const int bh = blkid >> 5;
    const int wc = blkid & 31;
    const int b  = bh >> 3;
    const int h  = bh & 7;
    const int tid  = threadIdx.x;
    const int wave = tid >> 6;
    const int lane = tid & 63;
    const int quad = lane >> 4;
    const int l16  = lane & 15;
    const int e7   = l16 & 7;

    const u16* qbase = qk + ((size_t)(bh * 2 + 0)) * LL * HDM;
    const u16* kbase = qk + ((size_t)(bh * 2 + 1)) * LL * HDM;
    const u16* vbase = v + (size_t)bh * HDM * LL;

    const int w0 = wc * 64 + wave * 16;   // this wave's 16 queries

    short8v qfrag[2];
    qfrag[0] = *(const short8v*)(qbase + (size_t)(w0 + l16) * HDM + quad * 8);
    qfrag[1] = *(const short8v*)(qbase + (size_t)(w0 + l16) * HDM + 32 + quad * 8);

    // ones-column B-frag for row-sum MFMA: B[n=l16][k]=1 iff n==0
    short8v vones;
    {
        short o1 = (l16 == 0) ? (short)0x3F80 : (short)0;
#pragma unroll
        for (int j = 0; j < 8; ++j) vones[j] = o1;
    }

    float4v oacc[4];
#pragma unroll
    for (int dt = 0; dt < 4; ++dt) oacc[dt] = (float4v){0.f, 0.f, 0.f, 0.f};
    float4v lacc = (float4v){0.f, 0.f, 0.f, 0.f};

    const int rbK   = wave * 32;
    const int lrowK = lane >> 3;          // 0..7
    const int gK    = ((lane & 7) ^ lrowK) * 8;
    const int rbV   = wave * 16;
    const int lrowV = lane >> 4;          // 0..3
    auto stage = [&](int ic, int buf) {
        const int m0 = ic * 128;
#pragma unroll
        for (int j = 0; j < 4; ++j) {
            gld_lds16(kbase + (size_t)(m0 + rbK + j * 8 + lrowK) * HDM + gK,
                      &kts[buf][rbK + j * 8][0]);
            const int vrow = j * 4 + lrowV;           // row&15 (rbV mult of 16)
            gld_lds16(vbase + (size_t)(rbV + vrow) * LL + m0 + (((lane & 15) ^ vrow) * 8),
                      &vts[buf][rbV + j * 4][0]);
        }
    };

    stage(0, 0);

    for (int ic = 0; ic < 16; ++ic) {
        const int cur = ic & 1;
        __syncthreads();   // drains vmcnt -> chunk ic staged; prev reads done

        if (ic < 15) stage(ic + 1, 1 - cur);

        // S = Q.K^T for all 8 m-tiles of this 128-m chunk
        float4v s[8];
#pragma unroll
        for (int mt = 0; mt < 8; ++mt) {
            s[mt] = (float4v){0.f, 0.f, 0.f, 0.f};
            short8v b0 = *(const short8v*)&kts[cur][mt * 16 + l16][((quad) ^ e7) * 8];
            s[mt] = __builtin_amdgcn_mfma_f32_16x16x32_bf16(qfrag[0], b0, s[mt], 0, 0, 0);
            short8v b1 = *(const short8v*)&kts[cur][mt * 16 + l16][((quad + 4) ^ e7) * 8];
            s[mt] = __builtin_amdgcn_mfma_f32_16x16x32_bf16(qfrag[1], b1, s[mt], 0, 0, 0);
        }

        // per 64-m half: P = exp2(S) -> pts -> A-frags -> lacc/oacc MFMA
#pragma unroll
        for (int g = 0; g < 2; ++g) {
#pragma unroll
            for (int mt4 = 0; mt4 < 4; ++mt4)
#pragma unroll
                for (int r = 0; r < 4; ++r)
                    pts[wave][quad * 4 + r][mt4 * 16 + l16] =
                        f2u(__builtin_amdgcn_exp2f(s[g * 4 + mt4][r]));

            short8v pa0 = *(const short8v*)&pts[wave][l16][quad * 8];
            short8v pa1 = *(const short8v*)&pts[wave][l16][32 + quad * 8];

            lacc = __builtin_amdgcn_mfma_f32_16x16x32_bf16(pa0, vones, lacc, 0, 0, 0);
            lacc = __builtin_amdgcn_mfma_f32_16x16x32_bf16(pa1, vones, lacc, 0, 0, 0);

#pragma unroll
            for (int dt = 0; dt < 4; ++dt) {
                short8v v0 = *(const short8v*)&vts[cur][dt * 16 + l16][((g * 8 + quad) ^ l16) * 8];
                oacc[dt] = __builtin_amdgcn_mfma_f32_16x16x32_bf16(pa0, v0, oacc[dt], 0, 0, 0);
                short8v v1 = *(const short8v*)&vts[cur][dt * 16 + l16][((g * 8 + 4 + quad) ^ l16) * 8];
                oacc[dt] = __builtin_amdgcn_mfma_f32_16x16x32_bf16(pa1, v1, oacc[dt], 0, 0, 0);
            }
        }
    }

    // l_run[r] lives in lane (quad, l16==0) of lacc[r]; broadcast per quad
    float inv[4];
#pragma unroll
    for (int r = 0; r < 4; ++r) {
        float lsum = __shfl(lacc[r], quad * 16);
        inv[r] = 1.f / lsum;
    }
    u16* ob = newv + (size_t)b * LL * 512 + h * 64;
#pragma unroll
    for (int dt = 0; dt < 4; ++dt)
#pragma unroll
        for (int r = 0; r < 4; ++r) {
            int w = w0 + quad * 4 + r;
            ob[(size_t)w * 512 + dt * 16 + l16] = f2u(oacc[dt][r] * inv[r]);
        }
}

// -------------------------------------------------------------------------
// Kernel 3: MFMA FC + swish + residual + layernorm, fused — R17-verified
// form (256 threads, full-K per wave). Output dtype per in-kernel
// detect_flag on raw x.
// -------------------------------------------------------------------------
__global__ __launch_bounds__(256) void fc_ln_mfma_kernel(
    const u16* __restrict__ newv,    // [4096][512] bf16
    const u16* __restrict__ fcw,     // [512][512] bf16
    const u16* __restrict__ fcb,     // [512]
    const u16* __restrict__ xp,      // [B][2050][512] padded bf16
    const u16* __restrict__ xraw,    // raw x input (dtype detect)
    void* __restrict__ out)          // bf16 or f32 per flag
{
    const int flag = detect_flag(xraw);
    const int l0 = blockIdx.x * 16;
    const int tid  = threadIdx.x;
    const int wave = tid >> 6;
    const int lane = tid & 63;
    const int quad = lane >> 4;
    const int l16  = lane & 15;
    const int col0 = wave * 128;

    const int bb_ = l0 >> 11;   // batch (16-row tiles never straddle)
    const size_t xbase = ((size_t)(bb_ * 2050 + (l0 & 2047) + 1)) * 512;

    __shared__ float psum[4][16], psq[4][16];

    short8v aF[16];
    const u16* arow = newv + (size_t)(l0 + l16) * 512 + quad * 8;
#pragma unroll
    for (int kc = 0; kc < 16; ++kc)
        aF[kc] = *(const short8v*)(arow + kc * 32);

    float4v acc[8];
#pragma unroll
    for (int nt = 0; nt < 8; ++nt) acc[nt] = (float4v){0.f, 0.f, 0.f, 0.f};

#pragma unroll
    for (int nt = 0; nt < 8; ++nt) {
        const u16* brow = fcw + (size_t)(col0 + nt * 16 + l16) * 512 + quad * 8;
#pragma unroll
        for (int kc = 0; kc < 16; ++kc) {
            short8v bF = *(const short8v*)(brow + kc * 32);
            acc[nt] = __builtin_amdgcn_mfma_f32_16x16x32_bf16(aF[kc], bF, acc[nt], 0, 0, 0);
        }
    }

    float z[8][4];
    float rs[4] = {0.f, 0.f, 0.f, 0.f}, rq[4] = {0.f, 0.f, 0.f, 0.f};
#pragma unroll
    for (int nt = 0; nt < 8; ++nt) {
        int col = col0 + nt * 16 + l16;
        float bb = b2f(fcb[col]);
#pragma unroll
        for (int r = 0; r < 4; ++r) {
            int row = quad * 4 + r;
            float y = acc[nt][r] + bb;
            float sw = y / (1.f + __expf(-y));    // swish
            float xv = b2f(xp[xbase + (size_t)row * 512 + col]);
            float zz = xv * 2.f + sw;
            z[nt][r] = zz;
            rs[r] += zz;
            rq[r] += zz * zz;
        }
    }
#pragma unroll
    for (int msk = 1; msk <= 8; msk <<= 1)
#pragma unroll
        for (int r = 0; r < 4; ++r) {
            rs[r] += __shfl_xor(rs[r], msk);
            rq[r] += __shfl_xor(rq[r], msk);
        }
    if (l16 == 0) {
#pragma unroll
        for (int r = 0; r < 4; ++r) {
            psum[wave][quad * 4 + r] = rs[r];
            psq[wave][quad * 4 + r]  = rq[r];
        }
    }
    __syncthreads();

    float mu[4], inv[4];
#pragma unroll
    for (int r = 0; r < 4; ++r) {
        int row = quad * 4 + r;
        float s = psum[0][row] + psum[1][row] + psum[2][row] + psum[3][row];
        float q = psq[0][row] + psq[1][row] + psq[2][row] + psq[3][row];
        float m = s * (1.f / 512.f);
        float var = q * (1.f / 512.f) - m * m;
        mu[r] = m;
        inv[r] = rsqrtf(var + 1e-5f);
    }

#pragma unroll
    for (int nt = 0; nt < 8; ++nt) {
        int col = col0 + nt * 16 + l16;
#pragma unroll
        for (int r = 0; r < 4; ++r) {
            int row = quad * 4 + r;
            float val = (z[nt][r] - mu[r]) * inv[r];
            if (flag) ((float*)out)[(size_t)(l0 + row) * 512 + col] = val;
            else      ((u16*)out)[(size_t)(l0 + row) * 512 + col] = f2u(val);
        }
    }
}

extern "C" void kernel_launch(void* const* d_in, const int* in_sizes, int n_in,
                              void* d_out, int out_size, void* d_ws, size_t ws_size,
                              hipStream_t stream) {
    (void)in_sizes; (void)n_in; (void)out_size; (void)ws_size;

    char* ws = (char*)d_ws;
    u16* xp   = (u16*)(ws + 256);        // [2][2050][512] 4,198,400 B -> ends 4,198,656
    u16* wtc  = (u16*)(ws + 4198656);    // [1536][1536] 4,718,592 B  -> ends 8,917,248
    u16* bc   = (u16*)(ws + 8917248);    // 3,072 B  -> ends 8,920,320
    u16* fwc  = (u16*)(ws + 8920320);    // 524,288 B -> ends 9,444,608
    u16* fbc  = (u16*)(ws + 9444608);    // 1,024 B  -> ends 9,445,632
    u16* qkb  = (u16*)(ws + 9445632);    // [16][2][2048][64] = 8 MB -> ends 17,834,240
    u16* vb   = (u16*)(ws + 17834240);   // [16][64][2048]    = 4 MB -> ends 22,028,544
    u16* nvc  = (u16*)(ws + 22028544);   // [2][2048][512]    = 4 MB -> ends 26,222,848

    // unified prep: 1024 (xpad) + 1152 (convw) + 129 (small) = 2305 blocks
    prep_kernel<<<dim3(2305), dim3(256), 0, stream>>>(
        d_in[0], d_in[1], d_in[2], d_in[3], d_in[4],
        xp, wtc, bc, fwc, fbc);

    conv_mfma_kernel<<<dim3(32 * 12), dim3(256), 0, stream>>>(xp, wtc, bc, qkb, vb);
    attn_mfma_kernel<<<dim3(BB * HH * (LL / 64)), dim3(256), 0, stream>>>(qkb, vb, nvc);
    fc_ln_mfma_kernel<<<dim3(256), dim3(256), 0, stream>>>(
        nvc, fwc, fbc, xp, (const u16*)d_in[0], d_out);
}